// Round 7
// baseline (502.647 us; speedup 1.0000x reference)
//
#include <hip/hip_runtime.h>

typedef unsigned long long u64;
typedef unsigned short ushort_t;
typedef unsigned int uint32;

#define NNODES 12288
#define WORDS 192    // 12288 / 64 bits per row
#define ELLW 256     // max neighbors per row (avg ~64)
#define ZROW NNODES  // zeroed pad row index
#define CHROWS (NNODES + 8)          // rows per chunk incl. pad
#define CHSZ (CHROWS * 32)           // elements per 32-col chunk (8 chunks)

typedef __attribute__((ext_vector_type(8))) short short8_t;   // 8 bf16 (4 VGPRs)
typedef __attribute__((ext_vector_type(4))) float f32x4;      // MFMA C/D frag

// ---- bf16 split helpers (RNE) ----
__device__ __forceinline__ ushort_t f2bf(float f) {
    uint32 u = __float_as_uint(f);
    return (ushort_t)((u + 0x7fffu + ((u >> 16) & 1u)) >> 16);
}
__device__ __forceinline__ float bf2f(ushort_t h) {
    return __uint_as_float(((uint32)h) << 16);
}

// ---------------- adjacency build: bitmask M[s][d], MT[d][s] ----------------
__global__ void build_mask_kernel(const int* __restrict__ ei, u64* __restrict__ M,
                                  u64* __restrict__ MT, int E) {
    int e = blockIdx.x * blockDim.x + threadIdx.x;
    if (e >= E) return;
    int s = ei[e];
    int d = ei[E + e];
    atomicOr(&M[(size_t)s * WORDS + (d >> 6)], 1ull << (d & 63));
    atomicOr(&MT[(size_t)d * WORDS + (s >> 6)], 1ull << (s & 63));
}

// ---------------- bitmask -> u16 ELL (padded to x8 with ZROW) ----------------
__global__ __launch_bounds__(256) void ell_fill_kernel(
        const u64* __restrict__ M, const u64* __restrict__ MT,
        ushort_t* __restrict__ ell, int* __restrict__ cnt, float* __restrict__ dinv) {
    int row = blockIdx.x * 4 + (threadIdx.x >> 6);
    int lane = threadIdx.x & 63;
    const u64* rM  = M  + (size_t)row * WORDS;
    const u64* rMT = MT + (size_t)row * WORDS;
    u64 wm[3], wt[3];
    int pm = 0, pt = 0;
    #pragma unroll
    for (int k = 0; k < 3; ++k) {
        wm[k] = rM[lane + 64 * k];  pm += __popcll(wm[k]);
        wt[k] = rMT[lane + 64 * k]; pt += __popcll(wt[k]);
    }
    int inclM = pm, inclT = pt;
    #pragma unroll
    for (int off = 1; off < 64; off <<= 1) {
        int ym = __shfl_up(inclM, off, 64);
        int yt = __shfl_up(inclT, off, 64);
        if (lane >= off) { inclM += ym; inclT += yt; }
    }
    int exclM = inclM - pm;
    int exclT = inclT - pt;
    int totM = __shfl(inclM, 63, 64);
    int totT = __shfl(inclT, 63, 64);
    ushort_t* out = ell + (size_t)row * ELLW;
    int pos = exclM;
    #pragma unroll
    for (int k = 0; k < 3; ++k) {
        u64 bits = wm[k];
        int base = (lane + 64 * k) << 6;
        while (bits) { out[pos++] = (ushort_t)(base + __builtin_ctzll(bits)); bits &= bits - 1; }
    }
    pos = totM + exclT;
    #pragma unroll
    for (int k = 0; k < 3; ++k) {
        u64 bits = wt[k];
        int base = (lane + 64 * k) << 6;
        while (bits) { out[pos++] = (ushort_t)(base + __builtin_ctzll(bits)); bits &= bits - 1; }
    }
    if (lane == 0) {
        int n = totM + totT;
        int np = (n + 7) & ~7;
        for (int p = n; p < np; ++p) out[p] = (ushort_t)ZROW;
        cnt[row] = n;
        dinv[row] = 1.0f / ((float)n + 1e-8f);
    }
}

// zero the 8 pad rows of each of the 8 chunks (2048 floats)
__global__ void clear_pad_kernel(float* __restrict__ xc) {
    int i = threadIdx.x;
    #pragma unroll
    for (int k = 0; k < 8; ++k) {
        int idx = k * 256 + i;              // [0, 2048)
        int chunk = idx >> 8;
        int rem = idx & 255;                // 8 rows x 32 cols
        xc[(size_t)chunk * CHSZ + (size_t)NNODES * 32 + rem] = 0.0f;
    }
}

// ---------------- weight prep: split all GEMM weights into bf16 hi/lo -------
__global__ void wprep_kernel(const float* __restrict__ e1, const float* __restrict__ e2,
                             const float* __restrict__ gi, const float* __restrict__ gl,
                             const float* __restrict__ go, const float* __restrict__ pj,
                             ushort_t* __restrict__ hi, ushort_t* __restrict__ lo) {
    int i = blockIdx.x * 256 + threadIdx.x;
    if (i >= 491520) return;
    float v;
    if (i < 131072)      v = (i < 65536) ? e1[i] : e2[i - 65536];
    else if (i < 196608) v = gi[i - 131072];
    else if (i < 393216) v = gl[i - 196608];
    else if (i < 458752) v = go[i - 393216];
    else                 v = pj[i - 458752];
    ushort_t h = f2bf(v);
    hi[i] = h;
    lo[i] = f2bf(v - bf2f(h));
}

// ---------------- generic fp32 -> bf16 hi/lo split (vectorized) ----------------
__global__ void conv_split_kernel(const float* __restrict__ src, ushort_t* __restrict__ hi,
                                  ushort_t* __restrict__ lo, int n4) {
    int i = blockIdx.x * 256 + threadIdx.x;
    if (i >= n4) return;
    float4 v = ((const float4*)src)[i];
    ushort_t h0 = f2bf(v.x), h1 = f2bf(v.y), h2 = f2bf(v.z), h3 = f2bf(v.w);
    ushort4 hv = make_ushort4(h0, h1, h2, h3);
    ushort4 lv = make_ushort4(f2bf(v.x - bf2f(h0)), f2bf(v.y - bf2f(h1)),
                              f2bf(v.z - bf2f(h2)), f2bf(v.w - bf2f(h3)));
    ((ushort4*)hi)[i] = hv;
    ((ushort4*)lo)[i] = lv;
}

// ---------------- XCD-pinned chunked spmm (padded ELL, nt gathers) ----------
// chunk = blockIdx.x & 7 ~= XCD id -> gathers stay in that XCD's 1.57 MB
// L2-resident chunk. Wave = 8 rows x 8 lanes (float4: 128 B line/gather).
// ELL padded to x8 with ZROW (zeroed row) -> no predication; 8-deep ILP;
// nontemporal loads bypass the always-missing 32 KB L1.
__global__ __launch_bounds__(256) void spmm_chunk_kernel(
        const float* __restrict__ xc, const ushort_t* __restrict__ ell,
        const int* __restrict__ cnt, const float* __restrict__ dinv,
        ushort_t* __restrict__ outh, ushort_t* __restrict__ outl) {
    int bx = blockIdx.x;
    int chunk = bx & 7;
    int rb = bx >> 3;
    int t = threadIdx.x;
    int lane = t & 63, w = t >> 6;
    int rloc = lane >> 3;
    int cl = lane & 7;
    int row = rb * 32 + w * 8 + rloc;
    const float* xb = xc + (size_t)chunk * CHSZ + (cl << 2);
    int n = cnt[row];
    int np = (n + 7) & ~7;
    const ushort_t* rell = ell + (size_t)row * ELLW;
    float ax = 0.f, ay = 0.f, az = 0.f, aw = 0.f;
    for (int i = 0; i < np; i += 8) {
        ushort4 ja = *(const ushort4*)&rell[i];
        ushort4 jb = *(const ushort4*)&rell[i + 4];
        f32x4 v0 = __builtin_nontemporal_load((const f32x4*)&xb[(size_t)ja.x * 32]);
        f32x4 v1 = __builtin_nontemporal_load((const f32x4*)&xb[(size_t)ja.y * 32]);
        f32x4 v2 = __builtin_nontemporal_load((const f32x4*)&xb[(size_t)ja.z * 32]);
        f32x4 v3 = __builtin_nontemporal_load((const f32x4*)&xb[(size_t)ja.w * 32]);
        f32x4 v4 = __builtin_nontemporal_load((const f32x4*)&xb[(size_t)jb.x * 32]);
        f32x4 v5 = __builtin_nontemporal_load((const f32x4*)&xb[(size_t)jb.y * 32]);
        f32x4 v6 = __builtin_nontemporal_load((const f32x4*)&xb[(size_t)jb.z * 32]);
        f32x4 v7 = __builtin_nontemporal_load((const f32x4*)&xb[(size_t)jb.w * 32]);
        ax += ((v0.x + v1.x) + (v2.x + v3.x)) + ((v4.x + v5.x) + (v6.x + v7.x));
        ay += ((v0.y + v1.y) + (v2.y + v3.y)) + ((v4.y + v5.y) + (v6.y + v7.y));
        az += ((v0.z + v1.z) + (v2.z + v3.z)) + ((v4.z + v5.z) + (v6.z + v7.z));
        aw += ((v0.w + v1.w) + (v2.w + v3.w)) + ((v4.w + v5.w) + (v6.w + v7.w));
    }
    float4 xr = *(const float4*)&xb[(size_t)row * 32];
    float dv = dinv[row];
    float sx = xr.x + dv * ax;
    float sy = xr.y + dv * ay;
    float sz = xr.z + dv * az;
    float sw = xr.w + dv * aw;
    ushort_t hx = f2bf(sx), hy = f2bf(sy), hz = f2bf(sz), hw = f2bf(sw);
    size_t o = (size_t)row * 256 + (chunk << 5) + (cl << 2);
    *(ushort4*)&outh[o] = make_ushort4(hx, hy, hz, hw);
    *(ushort4*)&outl[o] = make_ushort4(f2bf(sx - bf2f(hx)), f2bf(sy - bf2f(hy)),
                                       f2bf(sz - bf2f(hz)), f2bf(sw - bf2f(hw)));
}

// ---------------- split-bf16 MFMA GEMM, 128x64 tile, 64x32 per wave ----------
// per wave-chunk: 12 ds_read_b128 (~144 LDS-cyc) feed 24 MFMA (~115 cyc/SIMD)
// -- much better LDS:MFMA balance than the 64x64 tile. Dbuf 48 KB, staged via
// global_load_lds w16. XCD banding: xcd = bx&7 owns a contiguous row band.
__device__ __forceinline__ void stageA(const ushort_t* __restrict__ src, int rowbase,
                                       int K, int k0, ushort_t* dst, int w, int lane) {
    #pragma unroll
    for (int i = 0; i < 2; ++i) {
        int seg = w * 2 + i;
        int c16 = seg * 64 + lane;          // 512 16B-chunks cover 128x32 bf16
        int r = c16 >> 2, q = c16 & 3;
        const ushort_t* gp = src + (size_t)(rowbase + r) * K + k0 + q * 8;
        __builtin_amdgcn_global_load_lds(
            (const __attribute__((address_space(1))) void*)gp,
            (__attribute__((address_space(3))) void*)(dst + seg * 512), 16, 0, 0);
    }
}
__device__ __forceinline__ void stageB(const ushort_t* __restrict__ src, int colbase,
                                       int K, int k0, ushort_t* dst, int w, int lane) {
    int c16 = w * 64 + lane;                // 256 16B-chunks cover 64x32 bf16
    int r = c16 >> 2, q = c16 & 3;
    const ushort_t* gp = src + (size_t)(colbase + r) * K + k0 + q * 8;
    __builtin_amdgcn_global_load_lds(
        (const __attribute__((address_space(1))) void*)gp,
        (__attribute__((address_space(3))) void*)(dst + w * 512), 16, 0, 0);
}

template<bool RELU, bool F32OUT, bool BF16OUT, bool CHUNKX>
__global__ __launch_bounds__(256) void gemm_mfma_kernel(
        const ushort_t* __restrict__ Xhi, const ushort_t* __restrict__ Xlo,
        const ushort_t* __restrict__ Whi, const ushort_t* __restrict__ Wlo,
        const float* __restrict__ bias, float* __restrict__ Yf,
        ushort_t* __restrict__ Yhi, ushort_t* __restrict__ Ylo,
        int K, int Mcols, int CT) {
    __shared__ __align__(16) ushort_t ldsA[2][2][4096];   // [buf][hi/lo][128*32]
    __shared__ __align__(16) ushort_t ldsB[2][2][2048];   // [buf][hi/lo][64*32]
    int tid = threadIdx.x;
    int lane = tid & 63;
    int w = __builtin_amdgcn_readfirstlane(tid >> 6);
    int bx = blockIdx.x;
    int xcd = bx & 7;
    int k = bx >> 3;
    int RTper = (int)(gridDim.x >> 3) / CT;
    int rt = xcd * RTper + k / CT;
    int ct = k % CT;
    int row0 = rt * 128;
    int col0 = ct * 64;
    int wr = (w & 1) * 64;      // wave rows [wr, wr+64): 4 m-tiles
    int wc = (w >> 1) * 32;     // wave cols [wc, wc+32): 2 n-tiles
    int fr = lane & 15, fq = lane >> 4;

    f32x4 acc[4][2];
    #pragma unroll
    for (int a = 0; a < 4; ++a)
        #pragma unroll
        for (int b = 0; b < 2; ++b) {
            f32x4 z = {0.f, 0.f, 0.f, 0.f};
            acc[a][b] = z;
        }

    int NC = K >> 5;
    stageA(Xhi, row0, K, 0, &ldsA[0][0][0], w, lane);
    stageA(Xlo, row0, K, 0, &ldsA[0][1][0], w, lane);
    stageB(Whi, col0, K, 0, &ldsB[0][0][0], w, lane);
    stageB(Wlo, col0, K, 0, &ldsB[0][1][0], w, lane);
    __syncthreads();

    for (int c = 0; c < NC; ++c) {
        int bb = c & 1;
        if (c + 1 < NC) {
            int nb = (c + 1) & 1, k0 = (c + 1) << 5;
            stageA(Xhi, row0, K, k0, &ldsA[nb][0][0], w, lane);
            stageA(Xlo, row0, K, k0, &ldsA[nb][1][0], w, lane);
            stageB(Whi, col0, K, k0, &ldsB[nb][0][0], w, lane);
            stageB(Wlo, col0, K, k0, &ldsB[nb][1][0], w, lane);
        }
        const ushort_t* Ah = &ldsA[bb][0][0];
        const ushort_t* Al = &ldsA[bb][1][0];
        const ushort_t* Bh = &ldsB[bb][0][0];
        const ushort_t* Bl = &ldsB[bb][1][0];
        short8_t ah[4], al[4], bh[2], bl[2];
        #pragma unroll
        for (int t4 = 0; t4 < 4; ++t4) {
            int ao = (wr + 16 * t4 + fr) * 32 + fq * 8;
            ah[t4] = *(const short8_t*)&Ah[ao];
            al[t4] = *(const short8_t*)&Al[ao];
        }
        #pragma unroll
        for (int t2 = 0; t2 < 2; ++t2) {
            int bo = (wc + 16 * t2 + fr) * 32 + fq * 8;
            bh[t2] = *(const short8_t*)&Bh[bo];
            bl[t2] = *(const short8_t*)&Bl[bo];
        }
        #pragma unroll
        for (int mt = 0; mt < 4; ++mt)
            #pragma unroll
            for (int nt = 0; nt < 2; ++nt) {
                f32x4 a = acc[mt][nt];
                a = __builtin_amdgcn_mfma_f32_16x16x32_bf16(ah[mt], bh[nt], a, 0, 0, 0);
                a = __builtin_amdgcn_mfma_f32_16x16x32_bf16(ah[mt], bl[nt], a, 0, 0, 0);
                a = __builtin_amdgcn_mfma_f32_16x16x32_bf16(al[mt], bh[nt], a, 0, 0, 0);
                acc[mt][nt] = a;
            }
        __syncthreads();
    }

    // epilogue (C/D: col = lane&15, row = (lane>>4)*4 + reg)
    float bcol[2];
    #pragma unroll
    for (int nt = 0; nt < 2; ++nt) bcol[nt] = bias[col0 + wc + 16 * nt + fr];
    #pragma unroll
    for (int mt = 0; mt < 4; ++mt) {
        int gr0 = row0 + wr + 16 * mt + fq * 4;
        #pragma unroll
        for (int nt = 0; nt < 2; ++nt) {
            int gc = col0 + wc + 16 * nt + fr;
            #pragma unroll
            for (int e = 0; e < 4; ++e) {
                float v = acc[mt][nt][e] + bcol[nt];
                if (RELU) v = fmaxf(v, 0.0f);
                size_t off;
                if (CHUNKX)
                    off = (size_t)(gc >> 5) * CHSZ + (size_t)(gr0 + e) * 32 + (gc & 31);
                else
                    off = (size_t)(gr0 + e) * Mcols + gc;
                if (F32OUT) Yf[off] = v;
                if (BF16OUT) {
                    ushort_t h = f2bf(v);
                    Yhi[off] = h;
                    Ylo[off] = f2bf(v - bf2f(h));
                }
            }
        }
    }
}

// ---------------- legacy fp32 64x64 GEMM (hc1 head: K=128, M=64) ----------------
template<bool RELU>
__global__ __launch_bounds__(256) void gemm_kernel(
        const float* __restrict__ X, const float* __restrict__ W,
        const float* __restrict__ bias, float* __restrict__ Y,
        int K, int Mcols) {
    const int BK = 32, LDP = 68;
    __shared__ float Xs[BK * LDP];
    __shared__ float Ws[BK * LDP];
    int tid = threadIdx.x;
    int row0 = blockIdx.x * 64;
    int col0 = blockIdx.y * 64;
    int tx = tid & 15, ty = tid >> 4;
    float acc[4][4] = {};
    for (int k0 = 0; k0 < K; k0 += BK) {
        #pragma unroll
        for (int i = 0; i < 2; ++i) {
            int f = tid + i * 256;
            int r = f >> 3;
            int kk = (f & 7) << 2;
            float4 vx = *(const float4*)&X[(size_t)(row0 + r) * K + k0 + kk];
            float4 vw = *(const float4*)&W[(size_t)(col0 + r) * K + k0 + kk];
            Xs[(kk + 0) * LDP + r] = vx.x;
            Xs[(kk + 1) * LDP + r] = vx.y;
            Xs[(kk + 2) * LDP + r] = vx.z;
            Xs[(kk + 3) * LDP + r] = vx.w;
            Ws[(kk + 0) * LDP + r] = vw.x;
            Ws[(kk + 1) * LDP + r] = vw.y;
            Ws[(kk + 2) * LDP + r] = vw.z;
            Ws[(kk + 3) * LDP + r] = vw.w;
        }
        __syncthreads();
        #pragma unroll
        for (int k = 0; k < BK; ++k) {
            float4 a = *(const float4*)&Xs[k * LDP + (ty << 2)];
            float4 b = *(const float4*)&Ws[k * LDP + (tx << 2)];
            float av[4] = {a.x, a.y, a.z, a.w};
            float bv[4] = {b.x, b.y, b.z, b.w};
            #pragma unroll
            for (int i2 = 0; i2 < 4; ++i2)
                #pragma unroll
                for (int j2 = 0; j2 < 4; ++j2)
                    acc[i2][j2] += av[i2] * bv[j2];
        }
        __syncthreads();
    }
    float4 b4 = *(const float4*)&bias[col0 + (tx << 2)];
    float bb[4] = {b4.x, b4.y, b4.z, b4.w};
    #pragma unroll
    for (int i2 = 0; i2 < 4; ++i2) {
        int row = row0 + (ty << 2) + i2;
        float4 v;
        float* vp = (float*)&v;
        #pragma unroll
        for (int j2 = 0; j2 < 4; ++j2) {
            float tv = acc[i2][j2] + bb[j2];
            if (RELU) tv = fmaxf(tv, 0.0f);
            vp[j2] = tv;
        }
        *(float4*)&Y[(size_t)row * Mcols + col0 + (tx << 2)] = v;
    }
}

// tiny head: Y[N,M] = X[N,K] @ W[M,K]^T + b, K<=64, M small (8)
__global__ void gemm_small_kernel(const float* __restrict__ X, const float* __restrict__ W,
                                  const float* __restrict__ bias, float* __restrict__ Y,
                                  int N, int K, int M) {
    int idx = blockIdx.x * blockDim.x + threadIdx.x;
    if (idx >= N * M) return;
    int r = idx / M, m = idx % M;
    float s = bias[m];
    const float* xr = X + (size_t)r * K;
    const float* wr = W + (size_t)m * K;
    for (int k = 0; k < K; ++k) s += xr[k] * wr[k];
    Y[idx] = s;
}

__global__ void col_mean_kernel(const float* __restrict__ ne, float* __restrict__ gf, int N, int D) {
    int t = threadIdx.x;   // 0..127
    float s = 0.0f;
    for (int r = blockIdx.x; r < N; r += gridDim.x) s += ne[(size_t)r * D + t];
    atomicAdd(&gf[t], s * (1.0f / (float)N));
}

extern "C" void kernel_launch(void* const* d_in, const int* in_sizes, int n_in,
                              void* d_out, int out_size, void* d_ws, size_t ws_size,
                              hipStream_t stream) {
    const int N = NNODES;
    const float* nf     = (const float*)d_in[0];
    const int*   ei     = (const int*)d_in[1];
    const float* enc_w1 = (const float*)d_in[2];
    const float* enc_b1 = (const float*)d_in[3];
    const float* enc_w2 = (const float*)d_in[4];
    const float* enc_b2 = (const float*)d_in[5];
    const float* gin_w  = (const float*)d_in[6];
    const float* gin_b  = (const float*)d_in[7];
    const float* gl_w   = (const float*)d_in[8];
    const float* gl_b   = (const float*)d_in[9];
    const float* gout_w = (const float*)d_in[10];
    const float* gout_b = (const float*)d_in[11];
    const float* proj_w = (const float*)d_in[12];
    const float* proj_b = (const float*)d_in[13];
    const float* hc_w1  = (const float*)d_in[14];
    const float* hc_b1  = (const float*)d_in[15];
    const float* hc_w2  = (const float*)d_in[16];
    const float* hc_b2  = (const float*)d_in[17];
    const int E = in_sizes[1] >> 1;

    // workspace carve (bytes):
    // [0, 37748736): masks M+MT -- dead after ell_fill; then aliased by
    //                xc (chunk-major f32 w/ pad rows) + pairA/pairB hi/lo bf16
    // [37756928, ...): ell u16, cnt, dinv, W arenas, bufC (all launch-long)
    char* ws = (char*)d_ws;
    u64* M  = (u64*)ws;
    u64* MT = M + (size_t)N * WORDS;
    float*    xc  = (float*)ws;                                 // 12,591,104
    ushort_t* pAh = (ushort_t*)(ws + 12591104);                 //  6,291,456
    ushort_t* pAl = (ushort_t*)(ws + 18882560);
    ushort_t* pBh = (ushort_t*)(ws + 25174016);
    ushort_t* pBl = (ushort_t*)(ws + 31465472);                 // ends 37,756,928
    ushort_t* ell = (ushort_t*)(ws + 37756928);                 //  6,291,456
    int*      cntb = (int*)(ws + 44048384);
    float*    dinv = (float*)(ws + 44097536);
    ushort_t* Whi  = (ushort_t*)(ws + 44146688);                //    983,040
    ushort_t* Wlo  = (ushort_t*)(ws + 45129728);                //    983,040
    float*    bufC = (float*)(ws + 46112768);                   //  3,145,728

    float* ne     = (float*)d_out;                        // [N,128]
    float* logits = ne + (size_t)N * 128;                 // [N,8]
    float* gf     = logits + (size_t)N * 8;               // [128]

    hipMemsetAsync(M, 0, 2 * (size_t)N * WORDS * sizeof(u64), stream);
    hipMemsetAsync(gf, 0, 128 * sizeof(float), stream);

    build_mask_kernel<<<(E + 255) / 256, 256, 0, stream>>>(ei, M, MT, E);
    ell_fill_kernel<<<N / 4, 256, 0, stream>>>(M, MT, ell, cntb, dinv);
    // masks dead from here; xc/pairA/pairB may clobber them
    clear_pad_kernel<<<1, 256, 0, stream>>>(xc);

    wprep_kernel<<<1920, 256, 0, stream>>>(enc_w1, enc_w2, gin_w, gl_w, gout_w, proj_w,
                                           Whi, Wlo);
    conv_split_kernel<<<3072, 256, 0, stream>>>(nf, pBh, pBl, N * 64);   // nf -> pairB

    const int G256 = (N / 128) * 4;   // 384 blocks: 96 row-tiles x 4 col-tiles
    const int G128 = (N / 128) * 2;   // 192 blocks: 96 x 2
    // enc1: pairB -> pairA (relu, bf16 out)
    gemm_mfma_kernel<true, false, true, false><<<G256, 256, 0, stream>>>(
        pBh, pBl, Whi, Wlo, enc_b1, nullptr, pAh, pAl, 256, 256, 4);
    // enc2: pairA -> pairB (no relu, bf16 out)
    gemm_mfma_kernel<false, false, true, false><<<G256, 256, 0, stream>>>(
        pAh, pAl, Whi + 65536, Wlo + 65536, enc_b2, nullptr, pBh, pBl, 256, 256, 4);
    // gin: pairB -> xc (relu, f32 chunk-major out)
    gemm_mfma_kernel<true, true, false, true><<<G256, 256, 0, stream>>>(
        pBh, pBl, Whi + 131072, Wlo + 131072, gin_b, xc, nullptr, nullptr, 256, 256, 4);

    for (int i = 0; i < 3; ++i) {
        spmm_chunk_kernel<<<(N / 32) * 8, 256, 0, stream>>>(xc, ell, cntb, dinv, pAh, pAl);
        if (i < 2) {
            gemm_mfma_kernel<true, true, false, true><<<G256, 256, 0, stream>>>(
                pAh, pAl, Whi + 196608 + 65536 * i, Wlo + 196608 + 65536 * i,
                gl_b + 256 * i, xc, nullptr, nullptr, 256, 256, 4);
        } else {
            gemm_mfma_kernel<true, false, true, false><<<G256, 256, 0, stream>>>(
                pAh, pAl, Whi + 196608 + 65536 * i, Wlo + 196608 + 65536 * i,
                gl_b + 256 * i, nullptr, pBh, pBl, 256, 256, 4);
        }
    }
    // gout: pairB -> pairA (no relu, bf16 out)
    gemm_mfma_kernel<false, false, true, false><<<G256, 256, 0, stream>>>(
        pBh, pBl, Whi + 393216, Wlo + 393216, gout_b, nullptr, pAh, pAl, 256, 256, 4);
    // proj: pairA -> ne f32 row-major (relu), M=128
    gemm_mfma_kernel<true, true, false, false><<<G128, 256, 0, stream>>>(
        pAh, pAl, Whi + 458752, Wlo + 458752, proj_b, ne, nullptr, nullptr, 256, 128, 2);
    // hc1: fp32 legacy (K=128, M=64)
    gemm_kernel<true><<<dim3(N / 64, 1), 256, 0, stream>>>(ne, hc_w1, hc_b1, bufC, 128, 64);
    gemm_small_kernel<<<(N * 8 + 255) / 256, 256, 0, stream>>>(bufC, hc_w2, hc_b2, logits, N, 64, 8);
    col_mean_kernel<<<192, 128, 0, stream>>>(ne, gf, N, 128);
}

// Round 8
// 461.593 us; speedup vs baseline: 1.0889x; 1.0889x over previous
//
#include <hip/hip_runtime.h>

typedef unsigned long long u64;
typedef unsigned short ushort_t;
typedef unsigned int uint32;

#define NNODES 12288
#define WORDS 192    // 12288 / 64 bits per row
#define ELLW 256     // max neighbors per row (avg ~64)
#define ZROW NNODES  // zeroed pad row index
#define CHROWS (NNODES + 8)          // rows per chunk incl. pad
#define CHSZ (CHROWS * 32)           // elements per 32-col chunk (8 chunks)
#define LDP 264      // padded LDS row stride (shorts): breaks 16-way b128 conflict

typedef __attribute__((ext_vector_type(8))) short short8_t;   // 8 bf16 (4 VGPRs)
typedef __attribute__((ext_vector_type(4))) float f32x4;      // MFMA C/D frag

// ---- bf16 split helpers (RNE) ----
__device__ __forceinline__ ushort_t f2bf(float f) {
    uint32 u = __float_as_uint(f);
    return (ushort_t)((u + 0x7fffu + ((u >> 16) & 1u)) >> 16);
}
__device__ __forceinline__ float bf2f(ushort_t h) {
    return __uint_as_float(((uint32)h) << 16);
}

// ---------------- adjacency build: bitmask M[s][d], MT[d][s] ----------------
__global__ void build_mask_kernel(const int* __restrict__ ei, u64* __restrict__ M,
                                  u64* __restrict__ MT, int E) {
    int e = blockIdx.x * blockDim.x + threadIdx.x;
    if (e >= E) return;
    int s = ei[e];
    int d = ei[E + e];
    atomicOr(&M[(size_t)s * WORDS + (d >> 6)], 1ull << (d & 63));
    atomicOr(&MT[(size_t)d * WORDS + (s >> 6)], 1ull << (s & 63));
}

// ---------------- bitmask -> u16 ELL (padded to x8 with ZROW) ----------------
__global__ __launch_bounds__(256) void ell_fill_kernel(
        const u64* __restrict__ M, const u64* __restrict__ MT,
        ushort_t* __restrict__ ell, int* __restrict__ cnt, float* __restrict__ dinv) {
    int row = blockIdx.x * 4 + (threadIdx.x >> 6);
    int lane = threadIdx.x & 63;
    const u64* rM  = M  + (size_t)row * WORDS;
    const u64* rMT = MT + (size_t)row * WORDS;
    u64 wm[3], wt[3];
    int pm = 0, pt = 0;
    #pragma unroll
    for (int k = 0; k < 3; ++k) {
        wm[k] = rM[lane + 64 * k];  pm += __popcll(wm[k]);
        wt[k] = rMT[lane + 64 * k]; pt += __popcll(wt[k]);
    }
    int inclM = pm, inclT = pt;
    #pragma unroll
    for (int off = 1; off < 64; off <<= 1) {
        int ym = __shfl_up(inclM, off, 64);
        int yt = __shfl_up(inclT, off, 64);
        if (lane >= off) { inclM += ym; inclT += yt; }
    }
    int exclM = inclM - pm;
    int exclT = inclT - pt;
    int totM = __shfl(inclM, 63, 64);
    int totT = __shfl(inclT, 63, 64);
    ushort_t* out = ell + (size_t)row * ELLW;
    int pos = exclM;
    #pragma unroll
    for (int k = 0; k < 3; ++k) {
        u64 bits = wm[k];
        int base = (lane + 64 * k) << 6;
        while (bits) { out[pos++] = (ushort_t)(base + __builtin_ctzll(bits)); bits &= bits - 1; }
    }
    pos = totM + exclT;
    #pragma unroll
    for (int k = 0; k < 3; ++k) {
        u64 bits = wt[k];
        int base = (lane + 64 * k) << 6;
        while (bits) { out[pos++] = (ushort_t)(base + __builtin_ctzll(bits)); bits &= bits - 1; }
    }
    if (lane == 0) {
        int n = totM + totT;
        int np = (n + 7) & ~7;
        for (int p = n; p < np; ++p) out[p] = (ushort_t)ZROW;
        cnt[row] = n;
        dinv[row] = 1.0f / ((float)n + 1e-8f);
    }
}

// zero the 8 pad rows of each of the 8 chunks (2048 floats)
__global__ void clear_pad_kernel(float* __restrict__ xc) {
    int i = threadIdx.x;
    #pragma unroll
    for (int k = 0; k < 8; ++k) {
        int idx = k * 256 + i;
        int chunk = idx >> 8;
        int rem = idx & 255;
        xc[(size_t)chunk * CHSZ + (size_t)NNODES * 32 + rem] = 0.0f;
    }
}

// ---------------- weight prep: split all GEMM weights into bf16 hi/lo -------
__global__ void wprep_kernel(const float* __restrict__ e1, const float* __restrict__ e2,
                             const float* __restrict__ gi, const float* __restrict__ gl,
                             const float* __restrict__ go, const float* __restrict__ pj,
                             ushort_t* __restrict__ hi, ushort_t* __restrict__ lo) {
    int i = blockIdx.x * 256 + threadIdx.x;
    if (i >= 491520) return;
    float v;
    if (i < 131072)      v = (i < 65536) ? e1[i] : e2[i - 65536];
    else if (i < 196608) v = gi[i - 131072];
    else if (i < 393216) v = gl[i - 196608];
    else if (i < 458752) v = go[i - 393216];
    else                 v = pj[i - 458752];
    ushort_t h = f2bf(v);
    hi[i] = h;
    lo[i] = f2bf(v - bf2f(h));
}

// ---------------- generic fp32 -> bf16 hi/lo split (vectorized) ----------------
__global__ void conv_split_kernel(const float* __restrict__ src, ushort_t* __restrict__ hi,
                                  ushort_t* __restrict__ lo, int n4) {
    int i = blockIdx.x * 256 + threadIdx.x;
    if (i >= n4) return;
    float4 v = ((const float4*)src)[i];
    ushort_t h0 = f2bf(v.x), h1 = f2bf(v.y), h2 = f2bf(v.z), h3 = f2bf(v.w);
    ushort4 hv = make_ushort4(h0, h1, h2, h3);
    ushort4 lv = make_ushort4(f2bf(v.x - bf2f(h0)), f2bf(v.y - bf2f(h1)),
                              f2bf(v.z - bf2f(h2)), f2bf(v.w - bf2f(h3)));
    ((ushort4*)hi)[i] = hv;
    ((ushort4*)lo)[i] = lv;
}

// ---------------- XCD-pinned chunked spmm (padded ELL, plain loads) ----------
// chunk = blockIdx.x & 7 ~= XCD id -> gathers stay in that XCD's 1.57 MB
// L2-resident chunk (round 6: FETCH 18.8 MB). Plain loads (nt loads evicted
// L2 and tripled FETCH -- round 7). Padded ELL -> no predication, 8-deep ILP.
__global__ __launch_bounds__(256) void spmm_chunk_kernel(
        const float* __restrict__ xc, const ushort_t* __restrict__ ell,
        const int* __restrict__ cnt, const float* __restrict__ dinv,
        ushort_t* __restrict__ outh, ushort_t* __restrict__ outl) {
    int bx = blockIdx.x;
    int chunk = bx & 7;
    int rb = bx >> 3;
    int t = threadIdx.x;
    int lane = t & 63, w = t >> 6;
    int rloc = lane >> 3;
    int cl = lane & 7;
    int row = rb * 32 + w * 8 + rloc;
    const float* xb = xc + (size_t)chunk * CHSZ + (cl << 2);
    int n = cnt[row];
    int np = (n + 7) & ~7;
    const ushort_t* rell = ell + (size_t)row * ELLW;
    float ax = 0.f, ay = 0.f, az = 0.f, aw = 0.f;
    for (int i = 0; i < np; i += 8) {
        ushort4 ja = *(const ushort4*)&rell[i];
        ushort4 jb = *(const ushort4*)&rell[i + 4];
        float4 v0 = *(const float4*)&xb[(size_t)ja.x * 32];
        float4 v1 = *(const float4*)&xb[(size_t)ja.y * 32];
        float4 v2 = *(const float4*)&xb[(size_t)ja.z * 32];
        float4 v3 = *(const float4*)&xb[(size_t)ja.w * 32];
        float4 v4 = *(const float4*)&xb[(size_t)jb.x * 32];
        float4 v5 = *(const float4*)&xb[(size_t)jb.y * 32];
        float4 v6 = *(const float4*)&xb[(size_t)jb.z * 32];
        float4 v7 = *(const float4*)&xb[(size_t)jb.w * 32];
        ax += ((v0.x + v1.x) + (v2.x + v3.x)) + ((v4.x + v5.x) + (v6.x + v7.x));
        ay += ((v0.y + v1.y) + (v2.y + v3.y)) + ((v4.y + v5.y) + (v6.y + v7.y));
        az += ((v0.z + v1.z) + (v2.z + v3.z)) + ((v4.z + v5.z) + (v6.z + v7.z));
        aw += ((v0.w + v1.w) + (v2.w + v3.w)) + ((v4.w + v5.w) + (v6.w + v7.w));
    }
    float4 xr = *(const float4*)&xb[(size_t)row * 32];
    float dv = dinv[row];
    float sx = xr.x + dv * ax;
    float sy = xr.y + dv * ay;
    float sz = xr.z + dv * az;
    float sw = xr.w + dv * aw;
    ushort_t hx = f2bf(sx), hy = f2bf(sy), hz = f2bf(sz), hw = f2bf(sw);
    size_t o = (size_t)row * 256 + (chunk << 5) + (cl << 2);
    *(ushort4*)&outh[o] = make_ushort4(hx, hy, hz, hw);
    *(ushort4*)&outl[o] = make_ushort4(f2bf(sx - bf2f(hx)), f2bf(sy - bf2f(hy)),
                                       f2bf(sz - bf2f(hz)), f2bf(sw - bf2f(hw)));
}

// ---------------- barrier-free band GEMM (split-bf16 MFMA) ----------------
// Block = 32-row band x ALL Mcols. X band (hi+lo) staged to LDS ONCE (padded
// stride 264), one barrier, then k-loop with NO barriers: A-frags from static
// LDS, B-frags DIRECT from global W (wave pattern = 16 rows x 64 B, fully
// coalesced; W is 256 KB, L2-hot in every XCD since all 384 blocks read it).
// NTW = 16-col n-tiles per wave (4 -> Mcols 256, 2 -> Mcols 128).
template<bool RELU, bool F32OUT, bool BF16OUT, bool CHUNKX, int NTW>
__global__ __launch_bounds__(256) void gemm_band_kernel(
        const ushort_t* __restrict__ Xhi, const ushort_t* __restrict__ Xlo,
        const ushort_t* __restrict__ Whi, const ushort_t* __restrict__ Wlo,
        const float* __restrict__ bias, float* __restrict__ Yf,
        ushort_t* __restrict__ Yhi, ushort_t* __restrict__ Ylo, int Mcols) {
    __shared__ __align__(16) ushort_t Xh[32 * LDP];
    __shared__ __align__(16) ushort_t Xl[32 * LDP];
    int tid = threadIdx.x;
    int lane = tid & 63;
    int w = __builtin_amdgcn_readfirstlane(tid >> 6);
    int row0 = blockIdx.x * 32;
    int fr = lane & 15, fq = lane >> 4;

    // stage X band: 1024 16B-chunks per buffer (32 rows x 32 chunks)
    #pragma unroll
    for (int i = 0; i < 4; ++i) {
        int cid = i * 256 + tid;
        int r = cid >> 5, q = (cid & 31) << 3;
        short8_t vh = *(const short8_t*)&Xhi[(size_t)(row0 + r) * 256 + q];
        short8_t vl = *(const short8_t*)&Xlo[(size_t)(row0 + r) * 256 + q];
        *(short8_t*)&Xh[r * LDP + q] = vh;
        *(short8_t*)&Xl[r * LDP + q] = vl;
    }
    __syncthreads();

    int col0 = w * (16 * NTW);
    f32x4 acc[2][NTW];
    #pragma unroll
    for (int a = 0; a < 2; ++a)
        #pragma unroll
        for (int b = 0; b < NTW; ++b) {
            f32x4 z = {0.f, 0.f, 0.f, 0.f};
            acc[a][b] = z;
        }

    #pragma unroll
    for (int c = 0; c < 8; ++c) {
        short8_t ah[2], al[2], bh[NTW], bl[NTW];
        #pragma unroll
        for (int mt = 0; mt < 2; ++mt) {
            int ao = (16 * mt + fr) * LDP + c * 32 + fq * 8;
            ah[mt] = *(const short8_t*)&Xh[ao];
            al[mt] = *(const short8_t*)&Xl[ao];
        }
        #pragma unroll
        for (int nt = 0; nt < NTW; ++nt) {
            size_t bo = (size_t)(col0 + 16 * nt + fr) * 256 + c * 32 + fq * 8;
            bh[nt] = *(const short8_t*)&Whi[bo];
            bl[nt] = *(const short8_t*)&Wlo[bo];
        }
        #pragma unroll
        for (int mt = 0; mt < 2; ++mt)
            #pragma unroll
            for (int nt = 0; nt < NTW; ++nt) {
                f32x4 a = acc[mt][nt];
                a = __builtin_amdgcn_mfma_f32_16x16x32_bf16(ah[mt], bh[nt], a, 0, 0, 0);
                a = __builtin_amdgcn_mfma_f32_16x16x32_bf16(ah[mt], bl[nt], a, 0, 0, 0);
                a = __builtin_amdgcn_mfma_f32_16x16x32_bf16(al[mt], bh[nt], a, 0, 0, 0);
                acc[mt][nt] = a;
            }
    }

    // epilogue (C/D: col = lane&15, row = (lane>>4)*4 + reg)
    float bcol[NTW];
    #pragma unroll
    for (int nt = 0; nt < NTW; ++nt) bcol[nt] = bias[col0 + 16 * nt + fr];
    #pragma unroll
    for (int mt = 0; mt < 2; ++mt) {
        int gr0 = row0 + 16 * mt + fq * 4;
        #pragma unroll
        for (int nt = 0; nt < NTW; ++nt) {
            int gc = col0 + 16 * nt + fr;
            #pragma unroll
            for (int e = 0; e < 4; ++e) {
                float v = acc[mt][nt][e] + bcol[nt];
                if (RELU) v = fmaxf(v, 0.0f);
                size_t off;
                if (CHUNKX)
                    off = (size_t)(gc >> 5) * CHSZ + (size_t)(gr0 + e) * 32 + (gc & 31);
                else
                    off = (size_t)(gr0 + e) * Mcols + gc;
                if (F32OUT) Yf[off] = v;
                if (BF16OUT) {
                    ushort_t h = f2bf(v);
                    Yhi[off] = h;
                    Ylo[off] = f2bf(v - bf2f(h));
                }
            }
        }
    }
}

// ---------------- legacy fp32 64x64 GEMM (hc1 head: K=128, M=64) ----------------
template<bool RELU>
__global__ __launch_bounds__(256) void gemm_kernel(
        const float* __restrict__ X, const float* __restrict__ W,
        const float* __restrict__ bias, float* __restrict__ Y,
        int K, int Mcols) {
    const int BK = 32, LDPF = 68;
    __shared__ float Xs[BK * LDPF];
    __shared__ float Ws[BK * LDPF];
    int tid = threadIdx.x;
    int row0 = blockIdx.x * 64;
    int col0 = blockIdx.y * 64;
    int tx = tid & 15, ty = tid >> 4;
    float acc[4][4] = {};
    for (int k0 = 0; k0 < K; k0 += BK) {
        #pragma unroll
        for (int i = 0; i < 2; ++i) {
            int f = tid + i * 256;
            int r = f >> 3;
            int kk = (f & 7) << 2;
            float4 vx = *(const float4*)&X[(size_t)(row0 + r) * K + k0 + kk];
            float4 vw = *(const float4*)&W[(size_t)(col0 + r) * K + k0 + kk];
            Xs[(kk + 0) * LDPF + r] = vx.x;
            Xs[(kk + 1) * LDPF + r] = vx.y;
            Xs[(kk + 2) * LDPF + r] = vx.z;
            Xs[(kk + 3) * LDPF + r] = vx.w;
            Ws[(kk + 0) * LDPF + r] = vw.x;
            Ws[(kk + 1) * LDPF + r] = vw.y;
            Ws[(kk + 2) * LDPF + r] = vw.z;
            Ws[(kk + 3) * LDPF + r] = vw.w;
        }
        __syncthreads();
        #pragma unroll
        for (int k = 0; k < BK; ++k) {
            float4 a = *(const float4*)&Xs[k * LDPF + (ty << 2)];
            float4 b = *(const float4*)&Ws[k * LDPF + (tx << 2)];
            float av[4] = {a.x, a.y, a.z, a.w};
            float bv[4] = {b.x, b.y, b.z, b.w};
            #pragma unroll
            for (int i2 = 0; i2 < 4; ++i2)
                #pragma unroll
                for (int j2 = 0; j2 < 4; ++j2)
                    acc[i2][j2] += av[i2] * bv[j2];
        }
        __syncthreads();
    }
    float4 b4 = *(const float4*)&bias[col0 + (tx << 2)];
    float bb[4] = {b4.x, b4.y, b4.z, b4.w};
    #pragma unroll
    for (int i2 = 0; i2 < 4; ++i2) {
        int row = row0 + (ty << 2) + i2;
        float4 v;
        float* vp = (float*)&v;
        #pragma unroll
        for (int j2 = 0; j2 < 4; ++j2) {
            float tv = acc[i2][j2] + bb[j2];
            if (RELU) tv = fmaxf(tv, 0.0f);
            vp[j2] = tv;
        }
        *(float4*)&Y[(size_t)row * Mcols + col0 + (tx << 2)] = v;
    }
}

// tiny head: Y[N,M] = X[N,K] @ W[M,K]^T + b, K<=64, M small (8)
__global__ void gemm_small_kernel(const float* __restrict__ X, const float* __restrict__ W,
                                  const float* __restrict__ bias, float* __restrict__ Y,
                                  int N, int K, int M) {
    int idx = blockIdx.x * blockDim.x + threadIdx.x;
    if (idx >= N * M) return;
    int r = idx / M, m = idx % M;
    float s = bias[m];
    const float* xr = X + (size_t)r * K;
    const float* wr = W + (size_t)m * K;
    for (int k = 0; k < K; ++k) s += xr[k] * wr[k];
    Y[idx] = s;
}

__global__ void col_mean_kernel(const float* __restrict__ ne, float* __restrict__ gf, int N, int D) {
    int t = threadIdx.x;   // 0..127
    float s = 0.0f;
    for (int r = blockIdx.x; r < N; r += gridDim.x) s += ne[(size_t)r * D + t];
    atomicAdd(&gf[t], s * (1.0f / (float)N));
}

extern "C" void kernel_launch(void* const* d_in, const int* in_sizes, int n_in,
                              void* d_out, int out_size, void* d_ws, size_t ws_size,
                              hipStream_t stream) {
    const int N = NNODES;
    const float* nf     = (const float*)d_in[0];
    const int*   ei     = (const int*)d_in[1];
    const float* enc_w1 = (const float*)d_in[2];
    const float* enc_b1 = (const float*)d_in[3];
    const float* enc_w2 = (const float*)d_in[4];
    const float* enc_b2 = (const float*)d_in[5];
    const float* gin_w  = (const float*)d_in[6];
    const float* gin_b  = (const float*)d_in[7];
    const float* gl_w   = (const float*)d_in[8];
    const float* gl_b   = (const float*)d_in[9];
    const float* gout_w = (const float*)d_in[10];
    const float* gout_b = (const float*)d_in[11];
    const float* proj_w = (const float*)d_in[12];
    const float* proj_b = (const float*)d_in[13];
    const float* hc_w1  = (const float*)d_in[14];
    const float* hc_b1  = (const float*)d_in[15];
    const float* hc_w2  = (const float*)d_in[16];
    const float* hc_b2  = (const float*)d_in[17];
    const int E = in_sizes[1] >> 1;

    // workspace carve (bytes): same as round 7
    char* ws = (char*)d_ws;
    u64* M  = (u64*)ws;
    u64* MT = M + (size_t)N * WORDS;
    float*    xc  = (float*)ws;                                 // 12,591,104
    ushort_t* pAh = (ushort_t*)(ws + 12591104);                 //  6,291,456
    ushort_t* pAl = (ushort_t*)(ws + 18882560);
    ushort_t* pBh = (ushort_t*)(ws + 25174016);
    ushort_t* pBl = (ushort_t*)(ws + 31465472);                 // ends 37,756,928
    ushort_t* ell = (ushort_t*)(ws + 37756928);                 //  6,291,456
    int*      cntb = (int*)(ws + 44048384);
    float*    dinv = (float*)(ws + 44097536);
    ushort_t* Whi  = (ushort_t*)(ws + 44146688);                //    983,040
    ushort_t* Wlo  = (ushort_t*)(ws + 45129728);                //    983,040
    float*    bufC = (float*)(ws + 46112768);                   //  3,145,728

    float* ne     = (float*)d_out;                        // [N,128]
    float* logits = ne + (size_t)N * 128;                 // [N,8]
    float* gf     = logits + (size_t)N * 8;               // [128]

    hipMemsetAsync(M, 0, 2 * (size_t)N * WORDS * sizeof(u64), stream);
    hipMemsetAsync(gf, 0, 128 * sizeof(float), stream);

    build_mask_kernel<<<(E + 255) / 256, 256, 0, stream>>>(ei, M, MT, E);
    ell_fill_kernel<<<N / 4, 256, 0, stream>>>(M, MT, ell, cntb, dinv);
    // masks dead from here; xc/pairA/pairB may clobber them
    clear_pad_kernel<<<1, 256, 0, stream>>>(xc);

    wprep_kernel<<<1920, 256, 0, stream>>>(enc_w1, enc_w2, gin_w, gl_w, gout_w, proj_w,
                                           Whi, Wlo);
    conv_split_kernel<<<3072, 256, 0, stream>>>(nf, pBh, pBl, N * 64);   // nf -> pairB

    const int GB = N / 32;   // 384 band blocks
    // enc1: pairB -> pairA (relu, bf16 out)
    gemm_band_kernel<true, false, true, false, 4><<<GB, 256, 0, stream>>>(
        pBh, pBl, Whi, Wlo, enc_b1, nullptr, pAh, pAl, 256);
    // enc2: pairA -> pairB (no relu, bf16 out)
    gemm_band_kernel<false, false, true, false, 4><<<GB, 256, 0, stream>>>(
        pAh, pAl, Whi + 65536, Wlo + 65536, enc_b2, nullptr, pBh, pBl, 256);
    // gin: pairB -> xc (relu, f32 chunk-major out)
    gemm_band_kernel<true, true, false, true, 4><<<GB, 256, 0, stream>>>(
        pBh, pBl, Whi + 131072, Wlo + 131072, gin_b, xc, nullptr, nullptr, 256);

    for (int i = 0; i < 3; ++i) {
        spmm_chunk_kernel<<<(N / 32) * 8, 256, 0, stream>>>(xc, ell, cntb, dinv, pAh, pAl);
        if (i < 2) {
            gemm_band_kernel<true, true, false, true, 4><<<GB, 256, 0, stream>>>(
                pAh, pAl, Whi + 196608 + 65536 * i, Wlo + 196608 + 65536 * i,
                gl_b + 256 * i, xc, nullptr, nullptr, 256);
        } else {
            gemm_band_kernel<true, false, true, false, 4><<<GB, 256, 0, stream>>>(
                pAh, pAl, Whi + 196608 + 65536 * i, Wlo + 196608 + 65536 * i,
                gl_b + 256 * i, nullptr, pBh, pBl, 256);
        }
    }
    // gout: pairB -> pairA (no relu, bf16 out)
    gemm_band_kernel<false, false, true, false, 4><<<GB, 256, 0, stream>>>(
        pBh, pBl, Whi + 393216, Wlo + 393216, gout_b, nullptr, pAh, pAl, 256);
    // proj: pairA -> ne f32 row-major (relu), Mcols=128 -> NTW=2
    gemm_band_kernel<true, true, false, false, 2><<<GB, 256, 0, stream>>>(
        pAh, pAl, Whi + 458752, Wlo + 458752, proj_b, ne, nullptr, nullptr, 128);
    // hc1: fp32 legacy (K=128, M=64)
    gemm_kernel<true><<<dim3(N / 64, 1), 256, 0, stream>>>(ne, hc_w1, hc_b1, bufC, 128, 64);
    gemm_small_kernel<<<(N * 8 + 255) / 256, 256, 0, stream>>>(bufC, hc_w2, hc_b2, logits, N, 64, 8);
    col_mean_kernel<<<192, 128, 0, stream>>>(ne, gf, N, 128);
}

// Round 9
// 425.403 us; speedup vs baseline: 1.1816x; 1.0851x over previous
//
#include <hip/hip_runtime.h>

typedef unsigned long long u64;
typedef unsigned short ushort_t;
typedef unsigned int uint32;

#define NNODES 12288
#define WORDS 192    // 12288 / 64 bits per row
#define ELLW 256     // max neighbors per row (avg ~64)
#define ZROW NNODES  // zeroed pad row index
#define CHROWS (NNODES + 8)          // rows per chunk incl. pad
#define CHSZ (CHROWS * 32)           // elements per 32-col chunk (8 chunks)
#define LDP 264      // padded LDS row stride (shorts)

typedef __attribute__((ext_vector_type(8))) short short8_t;   // 8 bf16 (4 VGPRs)
typedef __attribute__((ext_vector_type(4))) float f32x4;      // MFMA C/D frag

// ---- bf16 split helpers (RNE) ----
__device__ __forceinline__ ushort_t f2bf(float f) {
    uint32 u = __float_as_uint(f);
    return (ushort_t)((u + 0x7fffu + ((u >> 16) & 1u)) >> 16);
}
__device__ __forceinline__ float bf2f(ushort_t h) {
    return __uint_as_float(((uint32)h) << 16);
}

// ---------------- adjacency build: bitmask M[s][d], MT[d][s] ----------------
__global__ void build_mask_kernel(const int* __restrict__ ei, u64* __restrict__ M,
                                  u64* __restrict__ MT, int E) {
    int e = blockIdx.x * blockDim.x + threadIdx.x;
    if (e >= E) return;
    int s = ei[e];
    int d = ei[E + e];
    atomicOr(&M[(size_t)s * WORDS + (d >> 6)], 1ull << (d & 63));
    atomicOr(&MT[(size_t)d * WORDS + (s >> 6)], 1ull << (s & 63));
}

// ---------------- bitmask -> u16 ELL (padded to x8 with ZROW) ----------------
__global__ __launch_bounds__(256) void ell_fill_kernel(
        const u64* __restrict__ M, const u64* __restrict__ MT,
        ushort_t* __restrict__ ell, int* __restrict__ cnt, float* __restrict__ dinv) {
    int row = blockIdx.x * 4 + (threadIdx.x >> 6);
    int lane = threadIdx.x & 63;
    const u64* rM  = M  + (size_t)row * WORDS;
    const u64* rMT = MT + (size_t)row * WORDS;
    u64 wm[3], wt[3];
    int pm = 0, pt = 0;
    #pragma unroll
    for (int k = 0; k < 3; ++k) {
        wm[k] = rM[lane + 64 * k];  pm += __popcll(wm[k]);
        wt[k] = rMT[lane + 64 * k]; pt += __popcll(wt[k]);
    }
    int inclM = pm, inclT = pt;
    #pragma unroll
    for (int off = 1; off < 64; off <<= 1) {
        int ym = __shfl_up(inclM, off, 64);
        int yt = __shfl_up(inclT, off, 64);
        if (lane >= off) { inclM += ym; inclT += yt; }
    }
    int exclM = inclM - pm;
    int exclT = inclT - pt;
    int totM = __shfl(inclM, 63, 64);
    int totT = __shfl(inclT, 63, 64);
    ushort_t* out = ell + (size_t)row * ELLW;
    int pos = exclM;
    #pragma unroll
    for (int k = 0; k < 3; ++k) {
        u64 bits = wm[k];
        int base = (lane + 64 * k) << 6;
        while (bits) { out[pos++] = (ushort_t)(base + __builtin_ctzll(bits)); bits &= bits - 1; }
    }
    pos = totM + exclT;
    #pragma unroll
    for (int k = 0; k < 3; ++k) {
        u64 bits = wt[k];
        int base = (lane + 64 * k) << 6;
        while (bits) { out[pos++] = (ushort_t)(base + __builtin_ctzll(bits)); bits &= bits - 1; }
    }
    if (lane == 0) {
        int n = totM + totT;
        int np = (n + 7) & ~7;
        for (int p = n; p < np; ++p) out[p] = (ushort_t)ZROW;
        cnt[row] = n;
        dinv[row] = 1.0f / ((float)n + 1e-8f);
    }
}

// zero the 8 pad rows of each of the 8 chunks
__global__ void clear_pad_kernel(float* __restrict__ xc) {
    int i = threadIdx.x;
    #pragma unroll
    for (int k = 0; k < 8; ++k) {
        int idx = k * 256 + i;
        int chunk = idx >> 8;
        int rem = idx & 255;
        xc[(size_t)chunk * CHSZ + (size_t)NNODES * 32 + rem] = 0.0f;
    }
}

// ---------------- weight prep: split all MFMA weights into bf16 hi/lo -------
// arena (elements): enc1 0 | enc2 65536 | gin 131072 | gl 196608(x3) |
//                   gout 393216 | proj 458752 | total 491520
__global__ void wprep_kernel(const float* __restrict__ e1, const float* __restrict__ e2,
                             const float* __restrict__ gi, const float* __restrict__ gl,
                             const float* __restrict__ go, const float* __restrict__ pj,
                             ushort_t* __restrict__ hi, ushort_t* __restrict__ lo) {
    int i = blockIdx.x * 256 + threadIdx.x;
    if (i >= 491520) return;
    float v;
    if (i < 131072)      v = (i < 65536) ? e1[i] : e2[i - 65536];
    else if (i < 196608) v = gi[i - 131072];
    else if (i < 393216) v = gl[i - 196608];
    else if (i < 458752) v = go[i - 393216];
    else                 v = pj[i - 458752];
    ushort_t h = f2bf(v);
    hi[i] = h;
    lo[i] = f2bf(v - bf2f(h));
}

// ---------------- XCD-pinned chunked spmm (round-8 version, unchanged) -------
__global__ __launch_bounds__(256) void spmm_chunk_kernel(
        const float* __restrict__ xc, const ushort_t* __restrict__ ell,
        const int* __restrict__ cnt, const float* __restrict__ dinv,
        ushort_t* __restrict__ outh, ushort_t* __restrict__ outl) {
    int bx = blockIdx.x;
    int chunk = bx & 7;
    int rb = bx >> 3;
    int t = threadIdx.x;
    int lane = t & 63, w = t >> 6;
    int rloc = lane >> 3;
    int cl = lane & 7;
    int row = rb * 32 + w * 8 + rloc;
    const float* xb = xc + (size_t)chunk * CHSZ + (cl << 2);
    int n = cnt[row];
    int np = (n + 7) & ~7;
    const ushort_t* rell = ell + (size_t)row * ELLW;
    float ax = 0.f, ay = 0.f, az = 0.f, aw = 0.f;
    for (int i = 0; i < np; i += 8) {
        ushort4 ja = *(const ushort4*)&rell[i];
        ushort4 jb = *(const ushort4*)&rell[i + 4];
        float4 v0 = *(const float4*)&xb[(size_t)ja.x * 32];
        float4 v1 = *(const float4*)&xb[(size_t)ja.y * 32];
        float4 v2 = *(const float4*)&xb[(size_t)ja.z * 32];
        float4 v3 = *(const float4*)&xb[(size_t)ja.w * 32];
        float4 v4 = *(const float4*)&xb[(size_t)jb.x * 32];
        float4 v5 = *(const float4*)&xb[(size_t)jb.y * 32];
        float4 v6 = *(const float4*)&xb[(size_t)jb.z * 32];
        float4 v7 = *(const float4*)&xb[(size_t)jb.w * 32];
        ax += ((v0.x + v1.x) + (v2.x + v3.x)) + ((v4.x + v5.x) + (v6.x + v7.x));
        ay += ((v0.y + v1.y) + (v2.y + v3.y)) + ((v4.y + v5.y) + (v6.y + v7.y));
        az += ((v0.z + v1.z) + (v2.z + v3.z)) + ((v4.z + v5.z) + (v6.z + v7.z));
        aw += ((v0.w + v1.w) + (v2.w + v3.w)) + ((v4.w + v5.w) + (v6.w + v7.w));
    }
    float4 xr = *(const float4*)&xb[(size_t)row * 32];
    float dv = dinv[row];
    float sx = xr.x + dv * ax;
    float sy = xr.y + dv * ay;
    float sz = xr.z + dv * az;
    float sw = xr.w + dv * aw;
    ushort_t hx = f2bf(sx), hy = f2bf(sy), hz = f2bf(sz), hw = f2bf(sw);
    size_t o = (size_t)row * 256 + (chunk << 5) + (cl << 2);
    *(ushort4*)&outh[o] = make_ushort4(hx, hy, hz, hw);
    *(ushort4*)&outl[o] = make_ushort4(f2bf(sx - bf2f(hx)), f2bf(sy - bf2f(hy)),
                                       f2bf(sz - bf2f(hz)), f2bf(sw - bf2f(hw)));
}

// ---------------- shared band-GEMM machinery ----------------
// A (32 rows x 256 k, hi/lo) in LDS stride LDP; B direct from L2-hot W
// (row-major [Mcols][256] bf16 hi/lo). unroll 2 bounds VGPR (no spill).
template<int NTW>
__device__ __forceinline__ void band_step(
        const ushort_t* Ah, const ushort_t* Al,
        const ushort_t* __restrict__ Wh, const ushort_t* __restrict__ Wl,
        int w, int lane, f32x4 (&acc)[2][NTW]) {
    int fr = lane & 15, fq = lane >> 4;
    int col0 = w * (16 * NTW);
    #pragma unroll 2
    for (int c = 0; c < 8; ++c) {
        short8_t ah[2], al[2], bh[NTW], bl[NTW];
        #pragma unroll
        for (int mt = 0; mt < 2; ++mt) {
            int ao = (16 * mt + fr) * LDP + c * 32 + fq * 8;
            ah[mt] = *(const short8_t*)&Ah[ao];
            al[mt] = *(const short8_t*)&Al[ao];
        }
        #pragma unroll
        for (int nt = 0; nt < NTW; ++nt) {
            size_t bo = (size_t)(col0 + 16 * nt + fr) * 256 + c * 32 + fq * 8;
            bh[nt] = *(const short8_t*)&Wh[bo];
            bl[nt] = *(const short8_t*)&Wl[bo];
        }
        #pragma unroll
        for (int mt = 0; mt < 2; ++mt)
            #pragma unroll
            for (int nt = 0; nt < NTW; ++nt) {
                f32x4 a = acc[mt][nt];
                a = __builtin_amdgcn_mfma_f32_16x16x32_bf16(ah[mt], bh[nt], a, 0, 0, 0);
                a = __builtin_amdgcn_mfma_f32_16x16x32_bf16(ah[mt], bl[nt], a, 0, 0, 0);
                a = __builtin_amdgcn_mfma_f32_16x16x32_bf16(al[mt], bh[nt], a, 0, 0, 0);
                acc[mt][nt] = a;
            }
    }
}

template<int NTW>
__device__ __forceinline__ void acc_zero(f32x4 (&acc)[2][NTW]) {
    #pragma unroll
    for (int a = 0; a < 2; ++a)
        #pragma unroll
        for (int b = 0; b < NTW; ++b) {
            f32x4 z = {0.f, 0.f, 0.f, 0.f};
            acc[a][b] = z;
        }
}

// bias + optional relu, split to hi/lo, store as next-stage LDS A
template<int NTW, bool RELU>
__device__ __forceinline__ void acc_to_lds(
        f32x4 (&acc)[2][NTW], const float* __restrict__ bias,
        int w, int lane, ushort_t* Ah, ushort_t* Al) {
    int fr = lane & 15, fq = lane >> 4;
    int col0 = w * (16 * NTW);
    #pragma unroll
    for (int mt = 0; mt < 2; ++mt)
        #pragma unroll
        for (int nt = 0; nt < NTW; ++nt) {
            int col = col0 + 16 * nt + fr;
            float bb = bias[col];
            #pragma unroll
            for (int e = 0; e < 4; ++e) {
                int r = 16 * mt + fq * 4 + e;
                float v = acc[mt][nt][e] + bb;
                if (RELU) v = fmaxf(v, 0.0f);
                ushort_t h = f2bf(v);
                Ah[r * LDP + col] = h;
                Al[r * LDP + col] = f2bf(v - bf2f(h));
            }
        }
}

// stage a pre-split bf16 pair band [N][256] into LDS
__device__ __forceinline__ void stage_pair(
        const ushort_t* __restrict__ Xh_, const ushort_t* __restrict__ Xl_,
        int row0, int tid, ushort_t* Ah, ushort_t* Al) {
    #pragma unroll
    for (int i = 0; i < 4; ++i) {
        int cid = i * 256 + tid;           // 1024 short8 slots
        int r = cid >> 5, q = (cid & 31) << 3;
        short8_t vh = *(const short8_t*)&Xh_[(size_t)(row0 + r) * 256 + q];
        short8_t vl = *(const short8_t*)&Xl_[(size_t)(row0 + r) * 256 + q];
        *(short8_t*)&Ah[r * LDP + q] = vh;
        *(short8_t*)&Al[r * LDP + q] = vl;
    }
}

// ---------------- fused encoder: nf -> enc1(relu) -> enc2 -> gin(relu) -> xc ----
__global__ __launch_bounds__(256) void fused_enc_kernel(
        const float* __restrict__ nf,
        const ushort_t* __restrict__ Wh, const ushort_t* __restrict__ Wl,
        const float* __restrict__ b1, const float* __restrict__ b2,
        const float* __restrict__ b3, float* __restrict__ xc) {
    __shared__ __align__(16) ushort_t Ah[32 * LDP];
    __shared__ __align__(16) ushort_t Al[32 * LDP];
    int tid = threadIdx.x;
    int lane = tid & 63;
    int w = __builtin_amdgcn_readfirstlane(tid >> 6);
    int row0 = blockIdx.x * 32;
    int fr = lane & 15, fq = lane >> 4;

    // stage nf band with on-the-fly hi/lo split
    int sr = tid >> 3, fo = tid & 7;
    #pragma unroll
    for (int i = 0; i < 8; ++i) {
        int c4 = fo + i * 8;               // float4 index 0..63
        float4 v = *(const float4*)&nf[(size_t)(row0 + sr) * 256 + c4 * 4];
        ushort_t h0 = f2bf(v.x), h1 = f2bf(v.y), h2 = f2bf(v.z), h3 = f2bf(v.w);
        *(ushort4*)&Ah[sr * LDP + c4 * 4] = make_ushort4(h0, h1, h2, h3);
        *(ushort4*)&Al[sr * LDP + c4 * 4] =
            make_ushort4(f2bf(v.x - bf2f(h0)), f2bf(v.y - bf2f(h1)),
                         f2bf(v.z - bf2f(h2)), f2bf(v.w - bf2f(h3)));
    }
    __syncthreads();

    f32x4 acc[2][4];
    // enc1 (relu)
    acc_zero<4>(acc);
    band_step<4>(Ah, Al, Wh, Wl, w, lane, acc);
    __syncthreads();
    acc_to_lds<4, true>(acc, b1, w, lane, Ah, Al);
    __syncthreads();
    // enc2 (no relu)
    acc_zero<4>(acc);
    band_step<4>(Ah, Al, Wh + 65536, Wl + 65536, w, lane, acc);
    __syncthreads();
    acc_to_lds<4, false>(acc, b2, w, lane, Ah, Al);
    __syncthreads();
    // gin (relu) -> xc chunk-major f32
    acc_zero<4>(acc);
    band_step<4>(Ah, Al, Wh + 131072, Wl + 131072, w, lane, acc);
    int col0 = w * 64;
    #pragma unroll
    for (int mt = 0; mt < 2; ++mt)
        #pragma unroll
        for (int nt = 0; nt < 4; ++nt) {
            int gc = col0 + 16 * nt + fr;
            float bb = b3[gc];
            #pragma unroll
            for (int e = 0; e < 4; ++e) {
                int gr = row0 + 16 * mt + fq * 4 + e;
                float v = fmaxf(acc[mt][nt][e] + bb, 0.0f);
                xc[(size_t)(gc >> 5) * CHSZ + (size_t)gr * 32 + (gc & 31)] = v;
            }
        }
}

// ---------------- gl layer band GEMM: pair -> relu -> xc f32 or pair bf16 -----
template<bool CHUNKX>
__global__ __launch_bounds__(256) void gl_band_kernel(
        const ushort_t* __restrict__ Xh_, const ushort_t* __restrict__ Xl_,
        const ushort_t* __restrict__ Wh, const ushort_t* __restrict__ Wl,
        const float* __restrict__ bias, float* __restrict__ xc,
        ushort_t* __restrict__ Yh, ushort_t* __restrict__ Yl) {
    __shared__ __align__(16) ushort_t Ah[32 * LDP];
    __shared__ __align__(16) ushort_t Al[32 * LDP];
    int tid = threadIdx.x;
    int lane = tid & 63;
    int w = __builtin_amdgcn_readfirstlane(tid >> 6);
    int row0 = blockIdx.x * 32;
    int fr = lane & 15, fq = lane >> 4;
    stage_pair(Xh_, Xl_, row0, tid, Ah, Al);
    __syncthreads();
    f32x4 acc[2][4];
    acc_zero<4>(acc);
    band_step<4>(Ah, Al, Wh, Wl, w, lane, acc);
    int col0 = w * 64;
    #pragma unroll
    for (int mt = 0; mt < 2; ++mt)
        #pragma unroll
        for (int nt = 0; nt < 4; ++nt) {
            int gc = col0 + 16 * nt + fr;
            float bb = bias[gc];
            #pragma unroll
            for (int e = 0; e < 4; ++e) {
                int gr = row0 + 16 * mt + fq * 4 + e;
                float v = fmaxf(acc[mt][nt][e] + bb, 0.0f);   // gl always relu
                if (CHUNKX) {
                    xc[(size_t)(gc >> 5) * CHSZ + (size_t)gr * 32 + (gc & 31)] = v;
                } else {
                    size_t off = (size_t)gr * 256 + gc;
                    ushort_t h = f2bf(v);
                    Yh[off] = h;
                    Yl[off] = f2bf(v - bf2f(h));
                }
            }
        }
}

// ---------------- fused output: gout -> proj(relu) -> hc1(relu) -> hc2 + mean ---
__global__ __launch_bounds__(256) void fused_out_kernel(
        const ushort_t* __restrict__ Xh_, const ushort_t* __restrict__ Xl_,
        const ushort_t* __restrict__ Wh, const ushort_t* __restrict__ Wl,
        const float* __restrict__ gout_b, const float* __restrict__ proj_b,
        const float* __restrict__ hc_w1, const float* __restrict__ hc_b1,
        const float* __restrict__ hc_w2, const float* __restrict__ hc_b2,
        float* __restrict__ ne, float* __restrict__ logits, float* __restrict__ gf) {
    __shared__ __align__(16) ushort_t Ah[32 * LDP];
    __shared__ __align__(16) ushort_t Al[32 * LDP];
    __shared__ __align__(16) float Pf[32 * 132];
    __shared__ __align__(16) float T1[32 * 68];
    int tid = threadIdx.x;
    int lane = tid & 63;
    int w = __builtin_amdgcn_readfirstlane(tid >> 6);
    int row0 = blockIdx.x * 32;
    int fr = lane & 15, fq = lane >> 4;
    stage_pair(Xh_, Xl_, row0, tid, Ah, Al);
    __syncthreads();

    // gout (no relu) -> LDS pair
    f32x4 acc[2][4];
    acc_zero<4>(acc);
    band_step<4>(Ah, Al, Wh + 393216, Wl + 393216, w, lane, acc);
    __syncthreads();
    acc_to_lds<4, false>(acc, gout_b, w, lane, Ah, Al);
    __syncthreads();

    // proj (relu), Mcols=128 -> ne global + Pf LDS
    f32x4 acc2[2][2];
    acc_zero<2>(acc2);
    band_step<2>(Ah, Al, Wh + 458752, Wl + 458752, w, lane, acc2);
    __syncthreads();   // all reads of Ah/Al done (we'll overwrite with hc_w1)
    int col0 = w * 32;
    #pragma unroll
    for (int mt = 0; mt < 2; ++mt)
        #pragma unroll
        for (int nt = 0; nt < 2; ++nt) {
            int gc = col0 + 16 * nt + fr;
            float bb = proj_b[gc];
            #pragma unroll
            for (int e = 0; e < 4; ++e) {
                int r = 16 * mt + fq * 4 + e;
                float v = fmaxf(acc2[mt][nt][e] + bb, 0.0f);
                ne[(size_t)(row0 + r) * 128 + gc] = v;
                Pf[r * 132 + gc] = v;
            }
        }
    // stage hc_w1 (64x128 f32 = 32 KB) into Ah/Al space, padded stride 132
    float* WL = (float*)Ah;
    #pragma unroll
    for (int i = 0; i < 8; ++i) {
        int j4 = i * 256 + tid;            // 2048 float4 slots
        int m = j4 >> 5, k4 = j4 & 31;
        float4 v = *(const float4*)&hc_w1[(size_t)m * 128 + k4 * 4];
        *(float4*)&WL[m * 132 + k4 * 4] = v;
    }
    __syncthreads();

    // hc1 (relu): 32x64, thread = (row r, col-group cg of 8)
    {
        int r = tid >> 3, cg = tid & 7;
        float a8[8];
        #pragma unroll
        for (int jj = 0; jj < 8; ++jj) a8[jj] = hc_b1[cg * 8 + jj];
        for (int k4 = 0; k4 < 32; ++k4) {
            float4 x = *(const float4*)&Pf[r * 132 + k4 * 4];
            #pragma unroll
            for (int jj = 0; jj < 8; ++jj) {
                float4 wv = *(const float4*)&WL[(cg * 8 + jj) * 132 + k4 * 4];
                a8[jj] += x.x * wv.x + x.y * wv.y + x.z * wv.z + x.w * wv.w;
            }
        }
        #pragma unroll
        for (int jj = 0; jj < 8; ++jj)
            T1[r * 68 + cg * 8 + jj] = fmaxf(a8[jj], 0.0f);
    }
    __syncthreads();

    // hc2: 32x8 logits
    {
        int r = tid >> 3, m = tid & 7;
        float s = hc_b2[m];
        #pragma unroll
        for (int k4 = 0; k4 < 16; ++k4) {
            float4 x = *(const float4*)&T1[r * 68 + k4 * 4];
            float4 wv = *(const float4*)&hc_w2[(size_t)m * 64 + k4 * 4];
            s += x.x * wv.x + x.y * wv.y + x.z * wv.z + x.w * wv.w;
        }
        logits[(size_t)(row0 + r) * 8 + m] = s;
    }

    // column-mean partial of ne band
    if (tid < 128) {
        float s = 0.0f;
        #pragma unroll 4
        for (int r = 0; r < 32; ++r) s += Pf[r * 132 + tid];
        atomicAdd(&gf[tid], s * (1.0f / (float)NNODES));
    }
}

extern "C" void kernel_launch(void* const* d_in, const int* in_sizes, int n_in,
                              void* d_out, int out_size, void* d_ws, size_t ws_size,
                              hipStream_t stream) {
    const int N = NNODES;
    const float* nf     = (const float*)d_in[0];
    const int*   ei     = (const int*)d_in[1];
    const float* enc_w1 = (const float*)d_in[2];
    const float* enc_b1 = (const float*)d_in[3];
    const float* enc_w2 = (const float*)d_in[4];
    const float* enc_b2 = (const float*)d_in[5];
    const float* gin_w  = (const float*)d_in[6];
    const float* gin_b  = (const float*)d_in[7];
    const float* gl_w   = (const float*)d_in[8];
    const float* gl_b   = (const float*)d_in[9];
    const float* gout_w = (const float*)d_in[10];
    const float* gout_b = (const float*)d_in[11];
    const float* proj_w = (const float*)d_in[12];
    const float* proj_b = (const float*)d_in[13];
    const float* hc_w1  = (const float*)d_in[14];
    const float* hc_b1  = (const float*)d_in[15];
    const float* hc_w2  = (const float*)d_in[16];
    const float* hc_b2  = (const float*)d_in[17];
    const int E = in_sizes[1] >> 1;

    // workspace carve (bytes): same as round 8
    char* ws = (char*)d_ws;
    u64* M  = (u64*)ws;
    u64* MT = M + (size_t)N * WORDS;
    float*    xc  = (float*)ws;                                 // 12,591,104
    ushort_t* pAh = (ushort_t*)(ws + 12591104);                 //  6,291,456
    ushort_t* pAl = (ushort_t*)(ws + 18882560);
    ushort_t* pBh = (ushort_t*)(ws + 25174016);
    ushort_t* pBl = (ushort_t*)(ws + 31465472);                 // ends 37,756,928
    ushort_t* ell = (ushort_t*)(ws + 37756928);                 //  6,291,456
    int*      cntb = (int*)(ws + 44048384);
    float*    dinv = (float*)(ws + 44097536);
    ushort_t* Whi  = (ushort_t*)(ws + 44146688);                //    983,040
    ushort_t* Wlo  = (ushort_t*)(ws + 45129728);                //    983,040

    float* ne     = (float*)d_out;                        // [N,128]
    float* logits = ne + (size_t)N * 128;                 // [N,8]
    float* gf     = logits + (size_t)N * 8;               // [128]

    hipMemsetAsync(M, 0, 2 * (size_t)N * WORDS * sizeof(u64), stream);
    hipMemsetAsync(gf, 0, 128 * sizeof(float), stream);

    build_mask_kernel<<<(E + 255) / 256, 256, 0, stream>>>(ei, M, MT, E);
    ell_fill_kernel<<<N / 4, 256, 0, stream>>>(M, MT, ell, cntb, dinv);
    // masks dead from here; xc/pairs may clobber them
    clear_pad_kernel<<<1, 256, 0, stream>>>(xc);
    wprep_kernel<<<1920, 256, 0, stream>>>(enc_w1, enc_w2, gin_w, gl_w, gout_w, proj_w,
                                           Whi, Wlo);

    const int GB = N / 32;   // 384 band blocks
    // encoder chain fused: nf -> xc
    fused_enc_kernel<<<GB, 256, 0, stream>>>(nf, Whi, Wlo, enc_b1, enc_b2, gin_b, xc);

    for (int i = 0; i < 3; ++i) {
        spmm_chunk_kernel<<<(N / 32) * 8, 256, 0, stream>>>(xc, ell, cntb, dinv, pAh, pAl);
        if (i < 2) {
            gl_band_kernel<true><<<GB, 256, 0, stream>>>(
                pAh, pAl, Whi + 196608 + 65536 * i, Wlo + 196608 + 65536 * i,
                gl_b + 256 * i, xc, nullptr, nullptr);
        } else {
            gl_band_kernel<false><<<GB, 256, 0, stream>>>(
                pAh, pAl, Whi + 196608 + 65536 * i, Wlo + 196608 + 65536 * i,
                gl_b + 256 * i, nullptr, pBh, pBl);
        }
    }
    // output chain fused: pB -> ne, logits, gf
    fused_out_kernel<<<GB, 256, 0, stream>>>(
        pBh, pBl, Whi, Wlo, gout_b, proj_b, hc_w1, hc_b1, hc_w2, hc_b2,
        ne, logits, gf);
}

// Round 10
// 422.653 us; speedup vs baseline: 1.1893x; 1.0065x over previous
//
#include <hip/hip_runtime.h>

typedef unsigned long long u64;
typedef unsigned short ushort_t;
typedef unsigned int uint32;

#define NNODES 12288
#define WORDS 192    // 12288 / 64 bits per row
#define ELLW 256     // max neighbors per row (avg ~64)
#define ZROW NNODES  // zeroed pad row index
#define CHROWS (NNODES + 8)          // rows per chunk incl. pad
#define CHSZ (CHROWS * 32)           // elements per 32-col chunk (8 chunks)
#define LDP 264      // padded LDS row stride (shorts)

typedef __attribute__((ext_vector_type(8))) short short8_t;   // 8 bf16 (4 VGPRs)
typedef __attribute__((ext_vector_type(4))) float f32x4;      // MFMA C/D frag

// ---- bf16 split helpers (RNE) ----
__device__ __forceinline__ ushort_t f2bf(float f) {
    uint32 u = __float_as_uint(f);
    return (ushort_t)((u + 0x7fffu + ((u >> 16) & 1u)) >> 16);
}
__device__ __forceinline__ float bf2f(ushort_t h) {
    return __uint_as_float(((uint32)h) << 16);
}

// ---------------- adjacency build: bitmask M[s][d], MT[d][s] ----------------
__global__ void build_mask_kernel(const int* __restrict__ ei, u64* __restrict__ M,
                                  u64* __restrict__ MT, int E) {
    int e = blockIdx.x * blockDim.x + threadIdx.x;
    if (e >= E) return;
    int s = ei[e];
    int d = ei[E + e];
    atomicOr(&M[(size_t)s * WORDS + (d >> 6)], 1ull << (d & 63));
    atomicOr(&MT[(size_t)d * WORDS + (s >> 6)], 1ull << (s & 63));
}

// ---------------- bitmask -> u16 ELL (padded to x8 with ZROW) ----------------
__global__ __launch_bounds__(256) void ell_fill_kernel(
        const u64* __restrict__ M, const u64* __restrict__ MT,
        ushort_t* __restrict__ ell, int* __restrict__ cnt, float* __restrict__ dinv) {
    int row = blockIdx.x * 4 + (threadIdx.x >> 6);
    int lane = threadIdx.x & 63;
    const u64* rM  = M  + (size_t)row * WORDS;
    const u64* rMT = MT + (size_t)row * WORDS;
    u64 wm[3], wt[3];
    int pm = 0, pt = 0;
    #pragma unroll
    for (int k = 0; k < 3; ++k) {
        wm[k] = rM[lane + 64 * k];  pm += __popcll(wm[k]);
        wt[k] = rMT[lane + 64 * k]; pt += __popcll(wt[k]);
    }
    int inclM = pm, inclT = pt;
    #pragma unroll
    for (int off = 1; off < 64; off <<= 1) {
        int ym = __shfl_up(inclM, off, 64);
        int yt = __shfl_up(inclT, off, 64);
        if (lane >= off) { inclM += ym; inclT += yt; }
    }
    int exclM = inclM - pm;
    int exclT = inclT - pt;
    int totM = __shfl(inclM, 63, 64);
    int totT = __shfl(inclT, 63, 64);
    ushort_t* out = ell + (size_t)row * ELLW;
    int pos = exclM;
    #pragma unroll
    for (int k = 0; k < 3; ++k) {
        u64 bits = wm[k];
        int base = (lane + 64 * k) << 6;
        while (bits) { out[pos++] = (ushort_t)(base + __builtin_ctzll(bits)); bits &= bits - 1; }
    }
    pos = totM + exclT;
    #pragma unroll
    for (int k = 0; k < 3; ++k) {
        u64 bits = wt[k];
        int base = (lane + 64 * k) << 6;
        while (bits) { out[pos++] = (ushort_t)(base + __builtin_ctzll(bits)); bits &= bits - 1; }
    }
    if (lane == 0) {
        int n = totM + totT;
        int np = (n + 7) & ~7;
        for (int p = n; p < np; ++p) out[p] = (ushort_t)ZROW;
        cnt[row] = n;
        dinv[row] = 1.0f / ((float)n + 1e-8f);
    }
}

// zero the 8 pad rows of each of the 8 chunks
__global__ void clear_pad_kernel(float* __restrict__ xc) {
    int i = threadIdx.x;
    #pragma unroll
    for (int k = 0; k < 8; ++k) {
        int idx = k * 256 + i;
        int chunk = idx >> 8;
        int rem = idx & 255;
        xc[(size_t)chunk * CHSZ + (size_t)NNODES * 32 + rem] = 0.0f;
    }
}

// ---------------- weight prep: split all MFMA weights into bf16 hi/lo -------
// arena (elements): enc1 0 | enc2 65536 | gin 131072 | gl 196608(x3) |
//                   gout 393216 | proj 458752 | total 491520
__global__ void wprep_kernel(const float* __restrict__ e1, const float* __restrict__ e2,
                             const float* __restrict__ gi, const float* __restrict__ gl,
                             const float* __restrict__ go, const float* __restrict__ pj,
                             ushort_t* __restrict__ hi, ushort_t* __restrict__ lo) {
    int i = blockIdx.x * 256 + threadIdx.x;
    if (i >= 491520) return;
    float v;
    if (i < 131072)      v = (i < 65536) ? e1[i] : e2[i - 65536];
    else if (i < 196608) v = gi[i - 131072];
    else if (i < 393216) v = gl[i - 196608];
    else if (i < 458752) v = go[i - 393216];
    else                 v = pj[i - 458752];
    ushort_t h = f2bf(v);
    hi[i] = h;
    lo[i] = f2bf(v - bf2f(h));
}

// ---------------- XCD-pinned chunked spmm (round-8 version, unchanged) -------
__global__ __launch_bounds__(256) void spmm_chunk_kernel(
        const float* __restrict__ xc, const ushort_t* __restrict__ ell,
        const int* __restrict__ cnt, const float* __restrict__ dinv,
        ushort_t* __restrict__ outh, ushort_t* __restrict__ outl) {
    int bx = blockIdx.x;
    int chunk = bx & 7;
    int rb = bx >> 3;
    int t = threadIdx.x;
    int lane = t & 63, w = t >> 6;
    int rloc = lane >> 3;
    int cl = lane & 7;
    int row = rb * 32 + w * 8 + rloc;
    const float* xb = xc + (size_t)chunk * CHSZ + (cl << 2);
    int n = cnt[row];
    int np = (n + 7) & ~7;
    const ushort_t* rell = ell + (size_t)row * ELLW;
    float ax = 0.f, ay = 0.f, az = 0.f, aw = 0.f;
    for (int i = 0; i < np; i += 8) {
        ushort4 ja = *(const ushort4*)&rell[i];
        ushort4 jb = *(const ushort4*)&rell[i + 4];
        float4 v0 = *(const float4*)&xb[(size_t)ja.x * 32];
        float4 v1 = *(const float4*)&xb[(size_t)ja.y * 32];
        float4 v2 = *(const float4*)&xb[(size_t)ja.z * 32];
        float4 v3 = *(const float4*)&xb[(size_t)ja.w * 32];
        float4 v4 = *(const float4*)&xb[(size_t)jb.x * 32];
        float4 v5 = *(const float4*)&xb[(size_t)jb.y * 32];
        float4 v6 = *(const float4*)&xb[(size_t)jb.z * 32];
        float4 v7 = *(const float4*)&xb[(size_t)jb.w * 32];
        ax += ((v0.x + v1.x) + (v2.x + v3.x)) + ((v4.x + v5.x) + (v6.x + v7.x));
        ay += ((v0.y + v1.y) + (v2.y + v3.y)) + ((v4.y + v5.y) + (v6.y + v7.y));
        az += ((v0.z + v1.z) + (v2.z + v3.z)) + ((v4.z + v5.z) + (v6.z + v7.z));
        aw += ((v0.w + v1.w) + (v2.w + v3.w)) + ((v4.w + v5.w) + (v6.w + v7.w));
    }
    float4 xr = *(const float4*)&xb[(size_t)row * 32];
    float dv = dinv[row];
    float sx = xr.x + dv * ax;
    float sy = xr.y + dv * ay;
    float sz = xr.z + dv * az;
    float sw = xr.w + dv * aw;
    ushort_t hx = f2bf(sx), hy = f2bf(sy), hz = f2bf(sz), hw = f2bf(sw);
    size_t o = (size_t)row * 256 + (chunk << 5) + (cl << 2);
    *(ushort4*)&outh[o] = make_ushort4(hx, hy, hz, hw);
    *(ushort4*)&outl[o] = make_ushort4(f2bf(sx - bf2f(hx)), f2bf(sy - bf2f(hy)),
                                       f2bf(sz - bf2f(hz)), f2bf(sw - bf2f(hw)));
}

// ---------------- shared band-GEMM machinery (512-thread / 8-wave blocks) ----
// A (32 rows x 256 k, hi/lo) in LDS stride LDP; B direct from L2-hot W with
// one-chunk-ahead register prefetch. Wave w owns cols [w*16*NTW, ...).
template<int NTW>
__device__ __forceinline__ void band_step(
        const ushort_t* Ah, const ushort_t* Al,
        const ushort_t* __restrict__ Wh, const ushort_t* __restrict__ Wl,
        int w, int lane, f32x4 (&acc)[2][NTW]) {
    int fr = lane & 15, fq = lane >> 4;
    int col0 = w * (16 * NTW);
    short8_t bh[NTW], bl[NTW];
    #pragma unroll
    for (int nt = 0; nt < NTW; ++nt) {
        size_t bo = (size_t)(col0 + 16 * nt + fr) * 256 + fq * 8;
        bh[nt] = *(const short8_t*)&Wh[bo];
        bl[nt] = *(const short8_t*)&Wl[bo];
    }
    #pragma unroll
    for (int c = 0; c < 8; ++c) {
        short8_t bhn[NTW], bln[NTW];
        if (c < 7) {
            #pragma unroll
            for (int nt = 0; nt < NTW; ++nt) {
                size_t bo = (size_t)(col0 + 16 * nt + fr) * 256 + (c + 1) * 32 + fq * 8;
                bhn[nt] = *(const short8_t*)&Wh[bo];
                bln[nt] = *(const short8_t*)&Wl[bo];
            }
        }
        short8_t ah[2], al[2];
        #pragma unroll
        for (int mt = 0; mt < 2; ++mt) {
            int ao = (16 * mt + fr) * LDP + c * 32 + fq * 8;
            ah[mt] = *(const short8_t*)&Ah[ao];
            al[mt] = *(const short8_t*)&Al[ao];
        }
        #pragma unroll
        for (int mt = 0; mt < 2; ++mt)
            #pragma unroll
            for (int nt = 0; nt < NTW; ++nt) {
                f32x4 a = acc[mt][nt];
                a = __builtin_amdgcn_mfma_f32_16x16x32_bf16(ah[mt], bh[nt], a, 0, 0, 0);
                a = __builtin_amdgcn_mfma_f32_16x16x32_bf16(ah[mt], bl[nt], a, 0, 0, 0);
                a = __builtin_amdgcn_mfma_f32_16x16x32_bf16(al[mt], bh[nt], a, 0, 0, 0);
                acc[mt][nt] = a;
            }
        if (c < 7) {
            #pragma unroll
            for (int nt = 0; nt < NTW; ++nt) { bh[nt] = bhn[nt]; bl[nt] = bln[nt]; }
        }
    }
}

template<int NTW>
__device__ __forceinline__ void acc_zero(f32x4 (&acc)[2][NTW]) {
    #pragma unroll
    for (int a = 0; a < 2; ++a)
        #pragma unroll
        for (int b = 0; b < NTW; ++b) {
            f32x4 z = {0.f, 0.f, 0.f, 0.f};
            acc[a][b] = z;
        }
}

// bias + optional relu, split to hi/lo, store as next-stage LDS A
template<int NTW, bool RELU>
__device__ __forceinline__ void acc_to_lds(
        f32x4 (&acc)[2][NTW], const float* __restrict__ bias,
        int w, int lane, ushort_t* Ah, ushort_t* Al) {
    int fr = lane & 15, fq = lane >> 4;
    int col0 = w * (16 * NTW);
    #pragma unroll
    for (int mt = 0; mt < 2; ++mt)
        #pragma unroll
        for (int nt = 0; nt < NTW; ++nt) {
            int col = col0 + 16 * nt + fr;
            float bb = bias[col];
            #pragma unroll
            for (int e = 0; e < 4; ++e) {
                int r = 16 * mt + fq * 4 + e;
                float v = acc[mt][nt][e] + bb;
                if (RELU) v = fmaxf(v, 0.0f);
                ushort_t h = f2bf(v);
                Ah[r * LDP + col] = h;
                Al[r * LDP + col] = f2bf(v - bf2f(h));
            }
        }
}

// stage a pre-split bf16 pair band [N][256] into LDS (512 threads)
__device__ __forceinline__ void stage_pair(
        const ushort_t* __restrict__ Xh_, const ushort_t* __restrict__ Xl_,
        int row0, int tid, ushort_t* Ah, ushort_t* Al) {
    #pragma unroll
    for (int i = 0; i < 2; ++i) {
        int cid = i * 512 + tid;           // 1024 short8 slots
        int r = cid >> 5, q = (cid & 31) << 3;
        short8_t vh = *(const short8_t*)&Xh_[(size_t)(row0 + r) * 256 + q];
        short8_t vl = *(const short8_t*)&Xl_[(size_t)(row0 + r) * 256 + q];
        *(short8_t*)&Ah[r * LDP + q] = vh;
        *(short8_t*)&Al[r * LDP + q] = vl;
    }
}

// ---------------- fused encoder: nf -> enc1(relu) -> enc2 -> gin(relu) -> xc ----
__global__ __launch_bounds__(512) void fused_enc_kernel(
        const float* __restrict__ nf,
        const ushort_t* __restrict__ Wh, const ushort_t* __restrict__ Wl,
        const float* __restrict__ b1, const float* __restrict__ b2,
        const float* __restrict__ b3, float* __restrict__ xc) {
    __shared__ __align__(16) ushort_t Ah[32 * LDP];
    __shared__ __align__(16) ushort_t Al[32 * LDP];
    int tid = threadIdx.x;
    int lane = tid & 63;
    int w = __builtin_amdgcn_readfirstlane(tid >> 6);   // 0..7
    int row0 = blockIdx.x * 32;
    int fr = lane & 15, fq = lane >> 4;

    // stage nf band with on-the-fly hi/lo split (2048 float4)
    #pragma unroll
    for (int i = 0; i < 4; ++i) {
        int cid = i * 512 + tid;
        int r = cid >> 6, c4 = cid & 63;
        float4 v = *(const float4*)&nf[(size_t)(row0 + r) * 256 + c4 * 4];
        ushort_t h0 = f2bf(v.x), h1 = f2bf(v.y), h2 = f2bf(v.z), h3 = f2bf(v.w);
        *(ushort4*)&Ah[r * LDP + c4 * 4] = make_ushort4(h0, h1, h2, h3);
        *(ushort4*)&Al[r * LDP + c4 * 4] =
            make_ushort4(f2bf(v.x - bf2f(h0)), f2bf(v.y - bf2f(h1)),
                         f2bf(v.z - bf2f(h2)), f2bf(v.w - bf2f(h3)));
    }
    __syncthreads();

    f32x4 acc[2][2];
    // enc1 (relu)
    acc_zero<2>(acc);
    band_step<2>(Ah, Al, Wh, Wl, w, lane, acc);
    __syncthreads();
    acc_to_lds<2, true>(acc, b1, w, lane, Ah, Al);
    __syncthreads();
    // enc2 (no relu)
    acc_zero<2>(acc);
    band_step<2>(Ah, Al, Wh + 65536, Wl + 65536, w, lane, acc);
    __syncthreads();
    acc_to_lds<2, false>(acc, b2, w, lane, Ah, Al);
    __syncthreads();
    // gin (relu) -> xc chunk-major f32
    acc_zero<2>(acc);
    band_step<2>(Ah, Al, Wh + 131072, Wl + 131072, w, lane, acc);
    int col0 = w * 32;
    #pragma unroll
    for (int mt = 0; mt < 2; ++mt)
        #pragma unroll
        for (int nt = 0; nt < 2; ++nt) {
            int gc = col0 + 16 * nt + fr;
            float bb = b3[gc];
            #pragma unroll
            for (int e = 0; e < 4; ++e) {
                int gr = row0 + 16 * mt + fq * 4 + e;
                float v = fmaxf(acc[mt][nt][e] + bb, 0.0f);
                xc[(size_t)(gc >> 5) * CHSZ + (size_t)gr * 32 + (gc & 31)] = v;
            }
        }
}

// ---------------- gl layer band GEMM: pair -> relu -> xc f32 or pair bf16 -----
template<bool CHUNKX>
__global__ __launch_bounds__(512) void gl_band_kernel(
        const ushort_t* __restrict__ Xh_, const ushort_t* __restrict__ Xl_,
        const ushort_t* __restrict__ Wh, const ushort_t* __restrict__ Wl,
        const float* __restrict__ bias, float* __restrict__ xc,
        ushort_t* __restrict__ Yh, ushort_t* __restrict__ Yl) {
    __shared__ __align__(16) ushort_t Ah[32 * LDP];
    __shared__ __align__(16) ushort_t Al[32 * LDP];
    int tid = threadIdx.x;
    int lane = tid & 63;
    int w = __builtin_amdgcn_readfirstlane(tid >> 6);
    int row0 = blockIdx.x * 32;
    int fr = lane & 15, fq = lane >> 4;
    stage_pair(Xh_, Xl_, row0, tid, Ah, Al);
    __syncthreads();
    f32x4 acc[2][2];
    acc_zero<2>(acc);
    band_step<2>(Ah, Al, Wh, Wl, w, lane, acc);
    int col0 = w * 32;
    #pragma unroll
    for (int mt = 0; mt < 2; ++mt)
        #pragma unroll
        for (int nt = 0; nt < 2; ++nt) {
            int gc = col0 + 16 * nt + fr;
            float bb = bias[gc];
            #pragma unroll
            for (int e = 0; e < 4; ++e) {
                int gr = row0 + 16 * mt + fq * 4 + e;
                float v = fmaxf(acc[mt][nt][e] + bb, 0.0f);   // gl always relu
                if (CHUNKX) {
                    xc[(size_t)(gc >> 5) * CHSZ + (size_t)gr * 32 + (gc & 31)] = v;
                } else {
                    size_t off = (size_t)gr * 256 + gc;
                    ushort_t h = f2bf(v);
                    Yh[off] = h;
                    Yl[off] = f2bf(v - bf2f(h));
                }
            }
        }
}

// ---------------- fused output: gout -> proj(relu) -> hc1(relu) -> hc2 + mean ---
__global__ __launch_bounds__(512) void fused_out_kernel(
        const ushort_t* __restrict__ Xh_, const ushort_t* __restrict__ Xl_,
        const ushort_t* __restrict__ Wh, const ushort_t* __restrict__ Wl,
        const float* __restrict__ gout_b, const float* __restrict__ proj_b,
        const float* __restrict__ hc_w1, const float* __restrict__ hc_b1,
        const float* __restrict__ hc_w2, const float* __restrict__ hc_b2,
        float* __restrict__ ne, float* __restrict__ logits, float* __restrict__ gf) {
    __shared__ __align__(16) ushort_t Ah[32 * LDP];
    __shared__ __align__(16) ushort_t Al[32 * LDP];
    __shared__ __align__(16) float Pf[32 * 132];
    __shared__ __align__(16) float T1[32 * 68];
    int tid = threadIdx.x;
    int lane = tid & 63;
    int w = __builtin_amdgcn_readfirstlane(tid >> 6);
    int row0 = blockIdx.x * 32;
    int fr = lane & 15, fq = lane >> 4;
    stage_pair(Xh_, Xl_, row0, tid, Ah, Al);
    __syncthreads();

    // gout (no relu) -> LDS pair
    f32x4 acc[2][2];
    acc_zero<2>(acc);
    band_step<2>(Ah, Al, Wh + 393216, Wl + 393216, w, lane, acc);
    __syncthreads();
    acc_to_lds<2, false>(acc, gout_b, w, lane, Ah, Al);
    __syncthreads();

    // proj (relu), Mcols=128: 8 waves x 16 cols -> ne global + Pf LDS
    f32x4 acc2[2][1];
    acc_zero<1>(acc2);
    band_step<1>(Ah, Al, Wh + 458752, Wl + 458752, w, lane, acc2);
    __syncthreads();   // all reads of Ah/Al done (we'll overwrite with hc_w1)
    int col0 = w * 16;
    #pragma unroll
    for (int mt = 0; mt < 2; ++mt) {
        int gc = col0 + fr;
        float bb = proj_b[gc];
        #pragma unroll
        for (int e = 0; e < 4; ++e) {
            int r = 16 * mt + fq * 4 + e;
            float v = fmaxf(acc2[mt][0][e] + bb, 0.0f);
            ne[(size_t)(row0 + r) * 128 + gc] = v;
            Pf[r * 132 + gc] = v;
        }
    }
    // stage hc_w1 (64x128 f32 = 32 KB) into Ah/Al space, padded stride 132
    float* WL = (float*)Ah;
    #pragma unroll
    for (int i = 0; i < 4; ++i) {
        int j4 = i * 512 + tid;            // 2048 float4 slots
        int m = j4 >> 5, k4 = j4 & 31;
        float4 v = *(const float4*)&hc_w1[(size_t)m * 128 + k4 * 4];
        *(float4*)&WL[m * 132 + k4 * 4] = v;
    }
    __syncthreads();

    // hc1 (relu): 32 rows x 64 cols; thread = (row, col-group of 4)
    {
        int r = tid >> 4, cg = tid & 15;
        float a4[4];
        #pragma unroll
        for (int jj = 0; jj < 4; ++jj) a4[jj] = hc_b1[cg * 4 + jj];
        for (int k4 = 0; k4 < 32; ++k4) {
            float4 x = *(const float4*)&Pf[r * 132 + k4 * 4];
            #pragma unroll
            for (int jj = 0; jj < 4; ++jj) {
                float4 wv = *(const float4*)&WL[(cg * 4 + jj) * 132 + k4 * 4];
                a4[jj] += x.x * wv.x + x.y * wv.y + x.z * wv.z + x.w * wv.w;
            }
        }
        #pragma unroll
        for (int jj = 0; jj < 4; ++jj)
            T1[r * 68 + cg * 4 + jj] = fmaxf(a4[jj], 0.0f);
    }
    __syncthreads();

    // hc2: 32x8 logits
    if (tid < 256) {
        int r = tid >> 3, m = tid & 7;
        float s = hc_b2[m];
        #pragma unroll
        for (int k4 = 0; k4 < 16; ++k4) {
            float4 x = *(const float4*)&T1[r * 68 + k4 * 4];
            float4 wv = *(const float4*)&hc_w2[(size_t)m * 64 + k4 * 4];
            s += x.x * wv.x + x.y * wv.y + x.z * wv.z + x.w * wv.w;
        }
        logits[(size_t)(row0 + r) * 8 + m] = s;
    }

    // column-mean partial of ne band
    if (tid < 128) {
        float s = 0.0f;
        #pragma unroll 4
        for (int r = 0; r < 32; ++r) s += Pf[r * 132 + tid];
        atomicAdd(&gf[tid], s * (1.0f / (float)NNODES));
    }
}

extern "C" void kernel_launch(void* const* d_in, const int* in_sizes, int n_in,
                              void* d_out, int out_size, void* d_ws, size_t ws_size,
                              hipStream_t stream) {
    const int N = NNODES;
    const float* nf     = (const float*)d_in[0];
    const int*   ei     = (const int*)d_in[1];
    const float* enc_w1 = (const float*)d_in[2];
    const float* enc_b1 = (const float*)d_in[3];
    const float* enc_w2 = (const float*)d_in[4];
    const float* enc_b2 = (const float*)d_in[5];
    const float* gin_w  = (const float*)d_in[6];
    const float* gin_b  = (const float*)d_in[7];
    const float* gl_w   = (const float*)d_in[8];
    const float* gl_b   = (const float*)d_in[9];
    const float* gout_w = (const float*)d_in[10];
    const float* gout_b = (const float*)d_in[11];
    const float* proj_w = (const float*)d_in[12];
    const float* proj_b = (const float*)d_in[13];
    const float* hc_w1  = (const float*)d_in[14];
    const float* hc_b1  = (const float*)d_in[15];
    const float* hc_w2  = (const float*)d_in[16];
    const float* hc_b2  = (const float*)d_in[17];
    const int E = in_sizes[1] >> 1;

    // workspace carve (bytes): same as round 8/9
    char* ws = (char*)d_ws;
    u64* M  = (u64*)ws;
    u64* MT = M + (size_t)N * WORDS;
    float*    xc  = (float*)ws;                                 // 12,591,104
    ushort_t* pAh = (ushort_t*)(ws + 12591104);                 //  6,291,456
    ushort_t* pAl = (ushort_t*)(ws + 18882560);
    ushort_t* pBh = (ushort_t*)(ws + 25174016);
    ushort_t* pBl = (ushort_t*)(ws + 31465472);                 // ends 37,756,928
    ushort_t* ell = (ushort_t*)(ws + 37756928);                 //  6,291,456
    int*      cntb = (int*)(ws + 44048384);
    float*    dinv = (float*)(ws + 44097536);
    ushort_t* Whi  = (ushort_t*)(ws + 44146688);                //    983,040
    ushort_t* Wlo  = (ushort_t*)(ws + 45129728);                //    983,040

    float* ne     = (float*)d_out;                        // [N,128]
    float* logits = ne + (size_t)N * 128;                 // [N,8]
    float* gf     = logits + (size_t)N * 8;               // [128]

    hipMemsetAsync(M, 0, 2 * (size_t)N * WORDS * sizeof(u64), stream);
    hipMemsetAsync(gf, 0, 128 * sizeof(float), stream);

    build_mask_kernel<<<(E + 255) / 256, 256, 0, stream>>>(ei, M, MT, E);
    ell_fill_kernel<<<N / 4, 256, 0, stream>>>(M, MT, ell, cntb, dinv);
    // masks dead from here; xc/pairs may clobber them
    clear_pad_kernel<<<1, 256, 0, stream>>>(xc);
    wprep_kernel<<<1920, 256, 0, stream>>>(enc_w1, enc_w2, gin_w, gl_w, gout_w, proj_w,
                                           Whi, Wlo);

    const int GB = N / 32;   // 384 band blocks (512 threads / 8 waves each)
    // encoder chain fused: nf -> xc
    fused_enc_kernel<<<GB, 512, 0, stream>>>(nf, Whi, Wlo, enc_b1, enc_b2, gin_b, xc);

    for (int i = 0; i < 3; ++i) {
        spmm_chunk_kernel<<<(N / 32) * 8, 256, 0, stream>>>(xc, ell, cntb, dinv, pAh, pAl);
        if (i < 2) {
            gl_band_kernel<true><<<GB, 512, 0, stream>>>(
                pAh, pAl, Whi + 196608 + 65536 * i, Wlo + 196608 + 65536 * i,
                gl_b + 256 * i, xc, nullptr, nullptr);
        } else {
            gl_band_kernel<false><<<GB, 512, 0, stream>>>(
                pAh, pAl, Whi + 196608 + 65536 * i, Wlo + 196608 + 65536 * i,
                gl_b + 256 * i, nullptr, pBh, pBl);
        }
    }
    // output chain fused: pB -> ne, logits, gf
    fused_out_kernel<<<GB, 512, 0, stream>>>(
        pBh, pBl, Whi, Wlo, gout_b, proj_b, hc_w1, hc_b1, hc_w2, hc_b2,
        ne, logits, gf);
}

// Round 11
// 399.712 us; speedup vs baseline: 1.2575x; 1.0574x over previous
//
#include <hip/hip_runtime.h>

typedef unsigned long long u64;
typedef unsigned short ushort_t;
typedef unsigned int uint32;

#define NNODES 12288
#define WORDS 192    // 12288 / 64 bits per row
#define ELLW 256     // max neighbors per row (avg ~64)
#define ZROW NNODES  // zeroed pad row index
#define CHROWS (NNODES + 8)          // rows per chunk incl. pad
#define CHSZ (CHROWS * 32)           // elements per 32-col chunk (8 chunks)

typedef __attribute__((ext_vector_type(8))) short short8_t;   // 8 bf16 (4 VGPRs)
typedef __attribute__((ext_vector_type(4))) float f32x4;      // MFMA C/D frag

// ---- bf16 split helpers (RNE) ----
__device__ __forceinline__ ushort_t f2bf(float f) {
    uint32 u = __float_as_uint(f);
    return (ushort_t)((u + 0x7fffu + ((u >> 16) & 1u)) >> 16);
}
__device__ __forceinline__ float bf2f(ushort_t h) {
    return __uint_as_float(((uint32)h) << 16);
}

// ---------------- adjacency build: bitmask M[s][d], MT[d][s] ----------------
__global__ void build_mask_kernel(const int* __restrict__ ei, u64* __restrict__ M,
                                  u64* __restrict__ MT, int E) {
    int e = blockIdx.x * blockDim.x + threadIdx.x;
    if (e >= E) return;
    int s = ei[e];
    int d = ei[E + e];
    atomicOr(&M[(size_t)s * WORDS + (d >> 6)], 1ull << (d & 63));
    atomicOr(&MT[(size_t)d * WORDS + (s >> 6)], 1ull << (s & 63));
}

// ---------------- bitmask -> u16 ELL (padded to x8 with ZROW) ----------------
__global__ __launch_bounds__(256) void ell_fill_kernel(
        const u64* __restrict__ M, const u64* __restrict__ MT,
        ushort_t* __restrict__ ell, int* __restrict__ cnt, float* __restrict__ dinv) {
    int row = blockIdx.x * 4 + (threadIdx.x >> 6);
    int lane = threadIdx.x & 63;
    const u64* rM  = M  + (size_t)row * WORDS;
    const u64* rMT = MT + (size_t)row * WORDS;
    u64 wm[3], wt[3];
    int pm = 0, pt = 0;
    #pragma unroll
    for (int k = 0; k < 3; ++k) {
        wm[k] = rM[lane + 64 * k];  pm += __popcll(wm[k]);
        wt[k] = rMT[lane + 64 * k]; pt += __popcll(wt[k]);
    }
    int inclM = pm, inclT = pt;
    #pragma unroll
    for (int off = 1; off < 64; off <<= 1) {
        int ym = __shfl_up(inclM, off, 64);
        int yt = __shfl_up(inclT, off, 64);
        if (lane >= off) { inclM += ym; inclT += yt; }
    }
    int exclM = inclM - pm;
    int exclT = inclT - pt;
    int totM = __shfl(inclM, 63, 64);
    int totT = __shfl(inclT, 63, 64);
    ushort_t* out = ell + (size_t)row * ELLW;
    int pos = exclM;
    #pragma unroll
    for (int k = 0; k < 3; ++k) {
        u64 bits = wm[k];
        int base = (lane + 64 * k) << 6;
        while (bits) { out[pos++] = (ushort_t)(base + __builtin_ctzll(bits)); bits &= bits - 1; }
    }
    pos = totM + exclT;
    #pragma unroll
    for (int k = 0; k < 3; ++k) {
        u64 bits = wt[k];
        int base = (lane + 64 * k) << 6;
        while (bits) { out[pos++] = (ushort_t)(base + __builtin_ctzll(bits)); bits &= bits - 1; }
    }
    if (lane == 0) {
        int n = totM + totT;
        int np = (n + 7) & ~7;
        for (int p = n; p < np; ++p) out[p] = (ushort_t)ZROW;
        cnt[row] = n;
        dinv[row] = 1.0f / ((float)n + 1e-8f);
    }
}

// zero the 8 pad rows of each of the 8 chunks
__global__ void clear_pad_kernel(float* __restrict__ xc) {
    int i = threadIdx.x;
    #pragma unroll
    for (int k = 0; k < 8; ++k) {
        int idx = k * 256 + i;
        int chunk = idx >> 8;
        int rem = idx & 255;
        xc[(size_t)chunk * CHSZ + (size_t)NNODES * 32 + rem] = 0.0f;
    }
}

// ---------------- weight prep: split + B-FRAGMENT SWIZZLE ----------------
// Per 65536-elem weight block (proj: 32768), tile (ct = col/16, c = k/32) is
// stored as 512 contiguous shorts in MFMA lane order:
//   off = base + (ct*8 + c)*512 + (fq*16 + fr)*8 + j   (col = ct*16+fr, k = c*32+fq*8+j)
// -> a wave's B-frag load is 1024 CONTIGUOUS bytes (8 sequential L2 lines).
__global__ void wprep_kernel(const float* __restrict__ e1, const float* __restrict__ e2,
                             const float* __restrict__ gi, const float* __restrict__ gl,
                             const float* __restrict__ go, const float* __restrict__ pj,
                             ushort_t* __restrict__ hi, ushort_t* __restrict__ lo) {
    int i = blockIdx.x * 256 + threadIdx.x;
    if (i >= 491520) return;
    float v;
    if (i < 131072)      v = (i < 65536) ? e1[i] : e2[i - 65536];
    else if (i < 196608) v = gi[i - 131072];
    else if (i < 393216) v = gl[i - 196608];
    else if (i < 458752) v = go[i - 393216];
    else                 v = pj[i - 458752];
    int base = (i < 458752) ? (i & ~65535) : 458752;
    int r = i - base;
    int col = r >> 8, k = r & 255;
    int ct = col >> 4, fr = col & 15;
    int c = k >> 5, fq = (k >> 3) & 3, j = k & 7;
    int o = base + (ct * 8 + c) * 512 + (fq * 16 + fr) * 8 + j;
    ushort_t h = f2bf(v);
    hi[o] = h;
    lo[o] = f2bf(v - bf2f(h));
}

// ---------------- XCD-pinned chunked spmm (unchanged, round-8 proven) -------
__global__ __launch_bounds__(256) void spmm_chunk_kernel(
        const float* __restrict__ xc, const ushort_t* __restrict__ ell,
        const int* __restrict__ cnt, const float* __restrict__ dinv,
        ushort_t* __restrict__ outh, ushort_t* __restrict__ outl) {
    int bx = blockIdx.x;
    int chunk = bx & 7;
    int rb = bx >> 3;
    int t = threadIdx.x;
    int lane = t & 63, w = t >> 6;
    int rloc = lane >> 3;
    int cl = lane & 7;
    int row = rb * 32 + w * 8 + rloc;
    const float* xb = xc + (size_t)chunk * CHSZ + (cl << 2);
    int n = cnt[row];
    int np = (n + 7) & ~7;
    const ushort_t* rell = ell + (size_t)row * ELLW;
    float ax = 0.f, ay = 0.f, az = 0.f, aw = 0.f;
    for (int i = 0; i < np; i += 8) {
        ushort4 ja = *(const ushort4*)&rell[i];
        ushort4 jb = *(const ushort4*)&rell[i + 4];
        float4 v0 = *(const float4*)&xb[(size_t)ja.x * 32];
        float4 v1 = *(const float4*)&xb[(size_t)ja.y * 32];
        float4 v2 = *(const float4*)&xb[(size_t)ja.z * 32];
        float4 v3 = *(const float4*)&xb[(size_t)ja.w * 32];
        float4 v4 = *(const float4*)&xb[(size_t)jb.x * 32];
        float4 v5 = *(const float4*)&xb[(size_t)jb.y * 32];
        float4 v6 = *(const float4*)&xb[(size_t)jb.z * 32];
        float4 v7 = *(const float4*)&xb[(size_t)jb.w * 32];
        ax += ((v0.x + v1.x) + (v2.x + v3.x)) + ((v4.x + v5.x) + (v6.x + v7.x));
        ay += ((v0.y + v1.y) + (v2.y + v3.y)) + ((v4.y + v5.y) + (v6.y + v7.y));
        az += ((v0.z + v1.z) + (v2.z + v3.z)) + ((v4.z + v5.z) + (v6.z + v7.z));
        aw += ((v0.w + v1.w) + (v2.w + v3.w)) + ((v4.w + v5.w) + (v6.w + v7.w));
    }
    float4 xr = *(const float4*)&xb[(size_t)row * 32];
    float dv = dinv[row];
    float sx = xr.x + dv * ax;
    float sy = xr.y + dv * ay;
    float sz = xr.z + dv * az;
    float sw = xr.w + dv * aw;
    ushort_t hx = f2bf(sx), hy = f2bf(sy), hz = f2bf(sz), hw = f2bf(sw);
    size_t o = (size_t)row * 256 + (chunk << 5) + (cl << 2);
    *(ushort4*)&outh[o] = make_ushort4(hx, hy, hz, hw);
    *(ushort4*)&outl[o] = make_ushort4(f2bf(sx - bf2f(hx)), f2bf(sy - bf2f(hy)),
                                       f2bf(sz - bf2f(hz)), f2bf(sw - bf2f(hw)));
}

// ---------------- band-GEMM machinery (frag-swizzled A in LDS, B from L2) ----
// A band (32 rows x 256 k) in LDS as 16 fragment tiles of 512 shorts:
//   tile t = c*2 + mt; addr = t*512 + lane*8  -> one conflict-free ds_read_b128.
// B loads: addr = ((ct*8 + c)*512 + lane*8) -> 1 KB contiguous per instruction.
template<int NTW>
__device__ __forceinline__ void band_step(
        const ushort_t* Ah, const ushort_t* Al,
        const ushort_t* __restrict__ Wh, const ushort_t* __restrict__ Wl,
        int w, int lane, f32x4 (&acc)[2][NTW]) {
    int ct0 = w * NTW;
    short8_t bh[NTW], bl[NTW];
    #pragma unroll
    for (int nt = 0; nt < NTW; ++nt) {
        size_t bo = (size_t)((ct0 + nt) * 8) * 512 + lane * 8;
        bh[nt] = *(const short8_t*)&Wh[bo];
        bl[nt] = *(const short8_t*)&Wl[bo];
    }
    #pragma unroll
    for (int c = 0; c < 8; ++c) {
        short8_t bhn[NTW], bln[NTW];
        if (c < 7) {
            #pragma unroll
            for (int nt = 0; nt < NTW; ++nt) {
                size_t bo = (size_t)((ct0 + nt) * 8 + c + 1) * 512 + lane * 8;
                bhn[nt] = *(const short8_t*)&Wh[bo];
                bln[nt] = *(const short8_t*)&Wl[bo];
            }
        }
        short8_t ah[2], al[2];
        #pragma unroll
        for (int mt = 0; mt < 2; ++mt) {
            int ao = (c * 2 + mt) * 512 + lane * 8;
            ah[mt] = *(const short8_t*)&Ah[ao];
            al[mt] = *(const short8_t*)&Al[ao];
        }
        #pragma unroll
        for (int mt = 0; mt < 2; ++mt)
            #pragma unroll
            for (int nt = 0; nt < NTW; ++nt) {
                f32x4 a = acc[mt][nt];
                a = __builtin_amdgcn_mfma_f32_16x16x32_bf16(ah[mt], bh[nt], a, 0, 0, 0);
                a = __builtin_amdgcn_mfma_f32_16x16x32_bf16(ah[mt], bl[nt], a, 0, 0, 0);
                a = __builtin_amdgcn_mfma_f32_16x16x32_bf16(al[mt], bh[nt], a, 0, 0, 0);
                acc[mt][nt] = a;
            }
        if (c < 7) {
            #pragma unroll
            for (int nt = 0; nt < NTW; ++nt) { bh[nt] = bhn[nt]; bl[nt] = bln[nt]; }
        }
    }
}

template<int NTW>
__device__ __forceinline__ void acc_zero(f32x4 (&acc)[2][NTW]) {
    #pragma unroll
    for (int a = 0; a < 2; ++a)
        #pragma unroll
        for (int b = 0; b < NTW; ++b) {
            f32x4 z = {0.f, 0.f, 0.f, 0.f};
            acc[a][b] = z;
        }
}

// bias + optional relu, split to hi/lo, store in FRAG layout for next step
template<int NTW, bool RELU>
__device__ __forceinline__ void acc_to_lds(
        f32x4 (&acc)[2][NTW], const float* __restrict__ bias,
        int w, int lane, ushort_t* Ah, ushort_t* Al) {
    int fr = lane & 15, fq = lane >> 4;
    int col0 = w * (16 * NTW);
    #pragma unroll
    for (int mt = 0; mt < 2; ++mt)
        #pragma unroll
        for (int nt = 0; nt < NTW; ++nt) {
            int col = col0 + 16 * nt + fr;         // next-step k index
            float bb = bias[col];
            int c = col >> 5, k32 = col & 31;
            int fqn = k32 >> 3, jn = k32 & 7;
            #pragma unroll
            for (int e = 0; e < 4; ++e) {
                int r = 16 * mt + fq * 4 + e;      // 0..31
                float v = acc[mt][nt][e] + bb;
                if (RELU) v = fmaxf(v, 0.0f);
                ushort_t h = f2bf(v);
                int addr = ((c * 2) + (r >> 4)) * 512 + (fqn * 16 + (r & 15)) * 8 + jn;
                Ah[addr] = h;
                Al[addr] = f2bf(v - bf2f(h));
            }
        }
}

// stage a pre-split bf16 pair band [N][256] (row-major) into FRAG LDS
__device__ __forceinline__ void stage_pair(
        const ushort_t* __restrict__ Xh_, const ushort_t* __restrict__ Xl_,
        int row0, int tid, ushort_t* Ah, ushort_t* Al) {
    #pragma unroll
    for (int i = 0; i < 2; ++i) {
        int s = i * 512 + tid;             // 1024 short8 slots
        int r = s >> 5;                    // row 0..31
        int kq = s & 31;                   // k-octet
        short8_t vh = *(const short8_t*)&Xh_[(size_t)(row0 + r) * 256 + kq * 8];
        short8_t vl = *(const short8_t*)&Xl_[(size_t)(row0 + r) * 256 + kq * 8];
        int c = kq >> 2, fq = kq & 3;
        int addr = (c * 2 + (r >> 4)) * 512 + (fq * 16 + (r & 15)) * 8;
        *(short8_t*)&Ah[addr] = vh;
        *(short8_t*)&Al[addr] = vl;
    }
}

// ---------------- fused encoder: nf -> enc1(relu) -> enc2 -> gin(relu) -> xc ----
__global__ __launch_bounds__(512) void fused_enc_kernel(
        const float* __restrict__ nf,
        const ushort_t* __restrict__ Wh, const ushort_t* __restrict__ Wl,
        const float* __restrict__ b1, const float* __restrict__ b2,
        const float* __restrict__ b3, float* __restrict__ xc) {
    __shared__ __align__(16) ushort_t Ah[8192];
    __shared__ __align__(16) ushort_t Al[8192];
    int tid = threadIdx.x;
    int lane = tid & 63;
    int w = __builtin_amdgcn_readfirstlane(tid >> 6);   // 0..7
    int row0 = blockIdx.x * 32;
    int fr = lane & 15, fq = lane >> 4;

    // stage nf band with on-the-fly hi/lo split into frag layout
    #pragma unroll
    for (int i = 0; i < 4; ++i) {
        int s = i * 512 + tid;             // 2048 float4 slots
        int r = s >> 6, k4 = s & 63;
        float4 v = *(const float4*)&nf[(size_t)(row0 + r) * 256 + k4 * 4];
        ushort_t h0 = f2bf(v.x), h1 = f2bf(v.y), h2 = f2bf(v.z), h3 = f2bf(v.w);
        int kq = k4 >> 1, half = (k4 & 1) * 4;
        int c = kq >> 2, fqs = kq & 3;
        int addr = (c * 2 + (r >> 4)) * 512 + (fqs * 16 + (r & 15)) * 8 + half;
        *(ushort4*)&Ah[addr] = make_ushort4(h0, h1, h2, h3);
        *(ushort4*)&Al[addr] =
            make_ushort4(f2bf(v.x - bf2f(h0)), f2bf(v.y - bf2f(h1)),
                         f2bf(v.z - bf2f(h2)), f2bf(v.w - bf2f(h3)));
    }
    __syncthreads();

    f32x4 acc[2][2];
    // enc1 (relu)
    acc_zero<2>(acc);
    band_step<2>(Ah, Al, Wh, Wl, w, lane, acc);
    __syncthreads();
    acc_to_lds<2, true>(acc, b1, w, lane, Ah, Al);
    __syncthreads();
    // enc2 (no relu)
    acc_zero<2>(acc);
    band_step<2>(Ah, Al, Wh + 65536, Wl + 65536, w, lane, acc);
    __syncthreads();
    acc_to_lds<2, false>(acc, b2, w, lane, Ah, Al);
    __syncthreads();
    // gin (relu) -> xc chunk-major f32
    acc_zero<2>(acc);
    band_step<2>(Ah, Al, Wh + 131072, Wl + 131072, w, lane, acc);
    int col0 = w * 32;
    #pragma unroll
    for (int mt = 0; mt < 2; ++mt)
        #pragma unroll
        for (int nt = 0; nt < 2; ++nt) {
            int gc = col0 + 16 * nt + fr;
            float bb = b3[gc];
            #pragma unroll
            for (int e = 0; e < 4; ++e) {
                int gr = row0 + 16 * mt + fq * 4 + e;
                float v = fmaxf(acc[mt][nt][e] + bb, 0.0f);
                xc[(size_t)(gc >> 5) * CHSZ + (size_t)gr * 32 + (gc & 31)] = v;
            }
        }
}

// ---------------- gl layer band GEMM: pair -> relu -> xc f32 or pair bf16 -----
template<bool CHUNKX>
__global__ __launch_bounds__(512) void gl_band_kernel(
        const ushort_t* __restrict__ Xh_, const ushort_t* __restrict__ Xl_,
        const ushort_t* __restrict__ Wh, const ushort_t* __restrict__ Wl,
        const float* __restrict__ bias, float* __restrict__ xc,
        ushort_t* __restrict__ Yh, ushort_t* __restrict__ Yl) {
    __shared__ __align__(16) ushort_t Ah[8192];
    __shared__ __align__(16) ushort_t Al[8192];
    int tid = threadIdx.x;
    int lane = tid & 63;
    int w = __builtin_amdgcn_readfirstlane(tid >> 6);
    int row0 = blockIdx.x * 32;
    int fr = lane & 15, fq = lane >> 4;
    stage_pair(Xh_, Xl_, row0, tid, Ah, Al);
    __syncthreads();
    f32x4 acc[2][2];
    acc_zero<2>(acc);
    band_step<2>(Ah, Al, Wh, Wl, w, lane, acc);
    int col0 = w * 32;
    #pragma unroll
    for (int mt = 0; mt < 2; ++mt)
        #pragma unroll
        for (int nt = 0; nt < 2; ++nt) {
            int gc = col0 + 16 * nt + fr;
            float bb = bias[gc];
            #pragma unroll
            for (int e = 0; e < 4; ++e) {
                int gr = row0 + 16 * mt + fq * 4 + e;
                float v = fmaxf(acc[mt][nt][e] + bb, 0.0f);   // gl always relu
                if (CHUNKX) {
                    xc[(size_t)(gc >> 5) * CHSZ + (size_t)gr * 32 + (gc & 31)] = v;
                } else {
                    size_t off = (size_t)gr * 256 + gc;
                    ushort_t h = f2bf(v);
                    Yh[off] = h;
                    Yl[off] = f2bf(v - bf2f(h));
                }
            }
        }
}

// ---------------- fused output: gout -> proj(relu) -> hc1(relu) -> hc2 + mean ---
__global__ __launch_bounds__(512) void fused_out_kernel(
        const ushort_t* __restrict__ Xh_, const ushort_t* __restrict__ Xl_,
        const ushort_t* __restrict__ Wh, const ushort_t* __restrict__ Wl,
        const float* __restrict__ gout_b, const float* __restrict__ proj_b,
        const float* __restrict__ hc_w1, const float* __restrict__ hc_b1,
        const float* __restrict__ hc_w2, const float* __restrict__ hc_b2,
        float* __restrict__ ne, float* __restrict__ logits, float* __restrict__ gf) {
    __shared__ __align__(16) ushort_t Ah[8192];
    __shared__ __align__(16) ushort_t Al[8192];
    __shared__ __align__(16) float Pf[32 * 132];
    __shared__ __align__(16) float T1[32 * 68];
    int tid = threadIdx.x;
    int lane = tid & 63;
    int w = __builtin_amdgcn_readfirstlane(tid >> 6);
    int row0 = blockIdx.x * 32;
    int fr = lane & 15, fq = lane >> 4;
    stage_pair(Xh_, Xl_, row0, tid, Ah, Al);
    __syncthreads();

    // gout (no relu) -> frag LDS pair
    f32x4 acc[2][2];
    acc_zero<2>(acc);
    band_step<2>(Ah, Al, Wh + 393216, Wl + 393216, w, lane, acc);
    __syncthreads();
    acc_to_lds<2, false>(acc, gout_b, w, lane, Ah, Al);
    __syncthreads();

    // proj (relu), Mcols=128: 8 waves x 16 cols -> ne global + Pf LDS
    f32x4 acc2[2][1];
    acc_zero<1>(acc2);
    band_step<1>(Ah, Al, Wh + 458752, Wl + 458752, w, lane, acc2);
    int col0 = w * 16;
    #pragma unroll
    for (int mt = 0; mt < 2; ++mt) {
        int gc = col0 + fr;
        float bb = proj_b[gc];
        #pragma unroll
        for (int e = 0; e < 4; ++e) {
            int r = 16 * mt + fq * 4 + e;
            float v = fmaxf(acc2[mt][0][e] + bb, 0.0f);
            ne[(size_t)(row0 + r) * 128 + gc] = v;
            Pf[r * 132 + gc] = v;
        }
    }
    __syncthreads();

    // hc1 (relu): 32 rows x 64 cols; thread = (row, col-group of 4); W from L2
    {
        int r = tid >> 4, cg = tid & 15;
        float a4[4];
        #pragma unroll
        for (int jj = 0; jj < 4; ++jj) a4[jj] = hc_b1[cg * 4 + jj];
        for (int k4 = 0; k4 < 32; ++k4) {
            float4 x = *(const float4*)&Pf[r * 132 + k4 * 4];
            #pragma unroll
            for (int jj = 0; jj < 4; ++jj) {
                float4 wv = *(const float4*)&hc_w1[(size_t)(cg * 4 + jj) * 128 + k4 * 4];
                a4[jj] += x.x * wv.x + x.y * wv.y + x.z * wv.z + x.w * wv.w;
            }
        }
        #pragma unroll
        for (int jj = 0; jj < 4; ++jj)
            T1[r * 68 + cg * 4 + jj] = fmaxf(a4[jj], 0.0f);
    }
    __syncthreads();

    // hc2: 32x8 logits
    if (tid < 256) {
        int r = tid >> 3, m = tid & 7;
        float s = hc_b2[m];
        #pragma unroll
        for (int k4 = 0; k4 < 16; ++k4) {
            float4 x = *(const float4*)&T1[r * 68 + k4 * 4];
            float4 wv = *(const float4*)&hc_w2[(size_t)m * 64 + k4 * 4];
            s += x.x * wv.x + x.y * wv.y + x.z * wv.z + x.w * wv.w;
        }
        logits[(size_t)(row0 + r) * 8 + m] = s;
    }

    // column-mean partial of ne band
    if (tid < 128) {
        float s = 0.0f;
        #pragma unroll 4
        for (int r = 0; r < 32; ++r) s += Pf[r * 132 + tid];
        atomicAdd(&gf[tid], s * (1.0f / (float)NNODES));
    }
}

extern "C" void kernel_launch(void* const* d_in, const int* in_sizes, int n_in,
                              void* d_out, int out_size, void* d_ws, size_t ws_size,
                              hipStream_t stream) {
    const int N = NNODES;
    const float* nf     = (const float*)d_in[0];
    const int*   ei     = (const int*)d_in[1];
    const float* enc_w1 = (const float*)d_in[2];
    const float* enc_b1 = (const float*)d_in[3];
    const float* enc_w2 = (const float*)d_in[4];
    const float* enc_b2 = (const float*)d_in[5];
    const float* gin_w  = (const float*)d_in[6];
    const float* gin_b  = (const float*)d_in[7];
    const float* gl_w   = (const float*)d_in[8];
    const float* gl_b   = (const float*)d_in[9];
    const float* gout_w = (const float*)d_in[10];
    const float* gout_b = (const float*)d_in[11];
    const float* proj_w = (const float*)d_in[12];
    const float* proj_b = (const float*)d_in[13];
    const float* hc_w1  = (const float*)d_in[14];
    const float* hc_b1  = (const float*)d_in[15];
    const float* hc_w2  = (const float*)d_in[16];
    const float* hc_b2  = (const float*)d_in[17];
    const int E = in_sizes[1] >> 1;

    // workspace carve (bytes): same as rounds 8-10
    char* ws = (char*)d_ws;
    u64* M  = (u64*)ws;
    u64* MT = M + (size_t)N * WORDS;
    float*    xc  = (float*)ws;                                 // 12,591,104
    ushort_t* pAh = (ushort_t*)(ws + 12591104);                 //  6,291,456
    ushort_t* pAl = (ushort_t*)(ws + 18882560);
    ushort_t* pBh = (ushort_t*)(ws + 25174016);
    ushort_t* pBl = (ushort_t*)(ws + 31465472);                 // ends 37,756,928
    ushort_t* ell = (ushort_t*)(ws + 37756928);                 //  6,291,456
    int*      cntb = (int*)(ws + 44048384);
    float*    dinv = (float*)(ws + 44097536);
    ushort_t* Whi  = (ushort_t*)(ws + 44146688);                //    983,040
    ushort_t* Wlo  = (ushort_t*)(ws + 45129728);                //    983,040

    float* ne     = (float*)d_out;                        // [N,128]
    float* logits = ne + (size_t)N * 128;                 // [N,8]
    float* gf     = logits + (size_t)N * 8;               // [128]

    hipMemsetAsync(M, 0, 2 * (size_t)N * WORDS * sizeof(u64), stream);
    hipMemsetAsync(gf, 0, 128 * sizeof(float), stream);

    build_mask_kernel<<<(E + 255) / 256, 256, 0, stream>>>(ei, M, MT, E);
    ell_fill_kernel<<<N / 4, 256, 0, stream>>>(M, MT, ell, cntb, dinv);
    // masks dead from here; xc/pairs may clobber them
    clear_pad_kernel<<<1, 256, 0, stream>>>(xc);
    wprep_kernel<<<1920, 256, 0, stream>>>(enc_w1, enc_w2, gin_w, gl_w, gout_w, proj_w,
                                           Whi, Wlo);

    const int GB = N / 32;   // 384 band blocks (512 threads / 8 waves each)
    // encoder chain fused: nf -> xc
    fused_enc_kernel<<<GB, 512, 0, stream>>>(nf, Whi, Wlo, enc_b1, enc_b2, gin_b, xc);

    for (int i = 0; i < 3; ++i) {
        spmm_chunk_kernel<<<(N / 32) * 8, 256, 0, stream>>>(xc, ell, cntb, dinv, pAh, pAl);
        if (i < 2) {
            gl_band_kernel<true><<<GB, 512, 0, stream>>>(
                pAh, pAl, Whi + 196608 + 65536 * i, Wlo + 196608 + 65536 * i,
                gl_b + 256 * i, xc, nullptr, nullptr);
        } else {
            gl_band_kernel<false><<<GB, 512, 0, stream>>>(
                pAh, pAl, Whi + 196608 + 65536 * i, Wlo + 196608 + 65536 * i,
                gl_b + 256 * i, nullptr, pBh, pBl);
        }
    }
    // output chain fused: pB -> ne, logits, gf
    fused_out_kernel<<<GB, 512, 0, stream>>>(
        pBh, pBl, Whi, Wlo, gout_b, proj_b, hc_w1, hc_b1, hc_w2, hc_b2,
        ne, logits, gf);
}

// Round 12
// 347.984 us; speedup vs baseline: 1.4445x; 1.1486x over previous
//
#include <hip/hip_runtime.h>

typedef unsigned long long u64;
typedef unsigned short ushort_t;
typedef unsigned int uint32;

#define NNODES 12288
#define WORDS 192    // 12288 / 64 bits per row
#define ELLW 256     // max neighbors per row (avg ~64)
#define ZROW NNODES  // zeroed pad row index
#define CHROWS (NNODES + 8)          // rows per chunk incl. pad
#define CHSZ (CHROWS * 32)           // elements per 32-col chunk (8 chunks)

typedef __attribute__((ext_vector_type(8))) short short8_t;   // 8 bf16 (4 VGPRs)
typedef __attribute__((ext_vector_type(4))) float f32x4;      // MFMA C/D frag

// ---- bf16 split helpers (RNE) ----
__device__ __forceinline__ ushort_t f2bf(float f) {
    uint32 u = __float_as_uint(f);
    return (ushort_t)((u + 0x7fffu + ((u >> 16) & 1u)) >> 16);
}
__device__ __forceinline__ float bf2f(ushort_t h) {
    return __uint_as_float(((uint32)h) << 16);
}

// ---------------- adjacency build: bitmask M[s][d], MT[d][s] ----------------
__global__ void build_mask_kernel(const int* __restrict__ ei, u64* __restrict__ M,
                                  u64* __restrict__ MT, int E) {
    int e = blockIdx.x * blockDim.x + threadIdx.x;
    if (e >= E) return;
    int s = ei[e];
    int d = ei[E + e];
    atomicOr(&M[(size_t)s * WORDS + (d >> 6)], 1ull << (d & 63));
    atomicOr(&MT[(size_t)d * WORDS + (s >> 6)], 1ull << (s & 63));
}

// ---------------- bitmask -> u16 ELL (padded to x8 with ZROW) ----------------
__global__ __launch_bounds__(256) void ell_fill_kernel(
        const u64* __restrict__ M, const u64* __restrict__ MT,
        ushort_t* __restrict__ ell, int* __restrict__ cnt, float* __restrict__ dinv) {
    int row = blockIdx.x * 4 + (threadIdx.x >> 6);
    int lane = threadIdx.x & 63;
    const u64* rM  = M  + (size_t)row * WORDS;
    const u64* rMT = MT + (size_t)row * WORDS;
    u64 wm[3], wt[3];
    int pm = 0, pt = 0;
    #pragma unroll
    for (int k = 0; k < 3; ++k) {
        wm[k] = rM[lane + 64 * k];  pm += __popcll(wm[k]);
        wt[k] = rMT[lane + 64 * k]; pt += __popcll(wt[k]);
    }
    int inclM = pm, inclT = pt;
    #pragma unroll
    for (int off = 1; off < 64; off <<= 1) {
        int ym = __shfl_up(inclM, off, 64);
        int yt = __shfl_up(inclT, off, 64);
        if (lane >= off) { inclM += ym; inclT += yt; }
    }
    int exclM = inclM - pm;
    int exclT = inclT - pt;
    int totM = __shfl(inclM, 63, 64);
    int totT = __shfl(inclT, 63, 64);
    ushort_t* out = ell + (size_t)row * ELLW;
    int pos = exclM;
    #pragma unroll
    for (int k = 0; k < 3; ++k) {
        u64 bits = wm[k];
        int base = (lane + 64 * k) << 6;
        while (bits) { out[pos++] = (ushort_t)(base + __builtin_ctzll(bits)); bits &= bits - 1; }
    }
    pos = totM + exclT;
    #pragma unroll
    for (int k = 0; k < 3; ++k) {
        u64 bits = wt[k];
        int base = (lane + 64 * k) << 6;
        while (bits) { out[pos++] = (ushort_t)(base + __builtin_ctzll(bits)); bits &= bits - 1; }
    }
    if (lane == 0) {
        int n = totM + totT;
        int np = (n + 7) & ~7;
        for (int p = n; p < np; ++p) out[p] = (ushort_t)ZROW;
        cnt[row] = n;
        dinv[row] = 1.0f / ((float)n + 1e-8f);
    }
}

// zero the 8 pad rows of each of the 8 chunks
__global__ void clear_pad_kernel(float* __restrict__ xc) {
    int i = threadIdx.x;
    #pragma unroll
    for (int k = 0; k < 8; ++k) {
        int idx = k * 256 + i;
        int chunk = idx >> 8;
        int rem = idx & 255;
        xc[(size_t)chunk * CHSZ + (size_t)NNODES * 32 + rem] = 0.0f;
    }
}

// ---------------- weight prep: split + B-FRAGMENT SWIZZLE ----------------
// Per 65536-elem weight block (proj: 32768), tile (ct = col/16, c = k/32) is
// stored as 512 contiguous shorts in MFMA lane order:
//   off = base + (ct*8 + c)*512 + (fq*16 + fr)*8 + j   (col = ct*16+fr, k = c*32+fq*8+j)
// -> a wave's B-frag load is 1024 CONTIGUOUS bytes (8 sequential L2 lines).
__global__ void wprep_kernel(const float* __restrict__ e1, const float* __restrict__ e2,
                             const float* __restrict__ gi, const float* __restrict__ gl,
                             const float* __restrict__ go, const float* __restrict__ pj,
                             ushort_t* __restrict__ hi, ushort_t* __restrict__ lo) {
    int i = blockIdx.x * 256 + threadIdx.x;
    if (i >= 491520) return;
    float v;
    if (i < 131072)      v = (i < 65536) ? e1[i] : e2[i - 65536];
    else if (i < 196608) v = gi[i - 131072];
    else if (i < 393216) v = gl[i - 196608];
    else if (i < 458752) v = go[i - 393216];
    else                 v = pj[i - 458752];
    int base = (i < 458752) ? (i & ~65535) : 458752;
    int r = i - base;
    int col = r >> 8, k = r & 255;
    int ct = col >> 4, fr = col & 15;
    int c = k >> 5, fq = (k >> 3) & 3, j = k & 7;
    int o = base + (ct * 8 + c) * 512 + (fq * 16 + fr) * 8 + j;
    ushort_t h = f2bf(v);
    hi[o] = h;
    lo[o] = f2bf(v - bf2f(h));
}

// ---------------- XCD-pinned chunked spmm (unchanged, round-8 proven) -------
__global__ __launch_bounds__(256) void spmm_chunk_kernel(
        const float* __restrict__ xc, const ushort_t* __restrict__ ell,
        const int* __restrict__ cnt, const float* __restrict__ dinv,
        ushort_t* __restrict__ outh, ushort_t* __restrict__ outl) {
    int bx = blockIdx.x;
    int chunk = bx & 7;
    int rb = bx >> 3;
    int t = threadIdx.x;
    int lane = t & 63, w = t >> 6;
    int rloc = lane >> 3;
    int cl = lane & 7;
    int row = rb * 32 + w * 8 + rloc;
    const float* xb = xc + (size_t)chunk * CHSZ + (cl << 2);
    int n = cnt[row];
    int np = (n + 7) & ~7;
    const ushort_t* rell = ell + (size_t)row * ELLW;
    float ax = 0.f, ay = 0.f, az = 0.f, aw = 0.f;
    for (int i = 0; i < np; i += 8) {
        ushort4 ja = *(const ushort4*)&rell[i];
        ushort4 jb = *(const ushort4*)&rell[i + 4];
        float4 v0 = *(const float4*)&xb[(size_t)ja.x * 32];
        float4 v1 = *(const float4*)&xb[(size_t)ja.y * 32];
        float4 v2 = *(const float4*)&xb[(size_t)ja.z * 32];
        float4 v3 = *(const float4*)&xb[(size_t)ja.w * 32];
        float4 v4 = *(const float4*)&xb[(size_t)jb.x * 32];
        float4 v5 = *(const float4*)&xb[(size_t)jb.y * 32];
        float4 v6 = *(const float4*)&xb[(size_t)jb.z * 32];
        float4 v7 = *(const float4*)&xb[(size_t)jb.w * 32];
        ax += ((v0.x + v1.x) + (v2.x + v3.x)) + ((v4.x + v5.x) + (v6.x + v7.x));
        ay += ((v0.y + v1.y) + (v2.y + v3.y)) + ((v4.y + v5.y) + (v6.y + v7.y));
        az += ((v0.z + v1.z) + (v2.z + v3.z)) + ((v4.z + v5.z) + (v6.z + v7.z));
        aw += ((v0.w + v1.w) + (v2.w + v3.w)) + ((v4.w + v5.w) + (v6.w + v7.w));
    }
    float4 xr = *(const float4*)&xb[(size_t)row * 32];
    float dv = dinv[row];
    float sx = xr.x + dv * ax;
    float sy = xr.y + dv * ay;
    float sz = xr.z + dv * az;
    float sw = xr.w + dv * aw;
    ushort_t hx = f2bf(sx), hy = f2bf(sy), hz = f2bf(sz), hw = f2bf(sw);
    size_t o = (size_t)row * 256 + (chunk << 5) + (cl << 2);
    *(ushort4*)&outh[o] = make_ushort4(hx, hy, hz, hw);
    *(ushort4*)&outl[o] = make_ushort4(f2bf(sx - bf2f(hx)), f2bf(sy - bf2f(hy)),
                                       f2bf(sz - bf2f(hz)), f2bf(sw - bf2f(hw)));
}

// ---------------- band-GEMM machinery (frag-swizzled A in LDS, B from L2) ----
template<int NTW>
__device__ __forceinline__ void band_step(
        const ushort_t* Ah, const ushort_t* Al,
        const ushort_t* __restrict__ Wh, const ushort_t* __restrict__ Wl,
        int w, int lane, f32x4 (&acc)[2][NTW]) {
    int ct0 = w * NTW;
    short8_t bh[NTW], bl[NTW];
    #pragma unroll
    for (int nt = 0; nt < NTW; ++nt) {
        size_t bo = (size_t)((ct0 + nt) * 8) * 512 + lane * 8;
        bh[nt] = *(const short8_t*)&Wh[bo];
        bl[nt] = *(const short8_t*)&Wl[bo];
    }
    #pragma unroll
    for (int c = 0; c < 8; ++c) {
        short8_t bhn[NTW], bln[NTW];
        if (c < 7) {
            #pragma unroll
            for (int nt = 0; nt < NTW; ++nt) {
                size_t bo = (size_t)((ct0 + nt) * 8 + c + 1) * 512 + lane * 8;
                bhn[nt] = *(const short8_t*)&Wh[bo];
                bln[nt] = *(const short8_t*)&Wl[bo];
            }
        }
        short8_t ah[2], al[2];
        #pragma unroll
        for (int mt = 0; mt < 2; ++mt) {
            int ao = (c * 2 + mt) * 512 + lane * 8;
            ah[mt] = *(const short8_t*)&Ah[ao];
            al[mt] = *(const short8_t*)&Al[ao];
        }
        #pragma unroll
        for (int mt = 0; mt < 2; ++mt)
            #pragma unroll
            for (int nt = 0; nt < NTW; ++nt) {
                f32x4 a = acc[mt][nt];
                a = __builtin_amdgcn_mfma_f32_16x16x32_bf16(ah[mt], bh[nt], a, 0, 0, 0);
                a = __builtin_amdgcn_mfma_f32_16x16x32_bf16(ah[mt], bl[nt], a, 0, 0, 0);
                a = __builtin_amdgcn_mfma_f32_16x16x32_bf16(al[mt], bh[nt], a, 0, 0, 0);
                acc[mt][nt] = a;
            }
        if (c < 7) {
            #pragma unroll
            for (int nt = 0; nt < NTW; ++nt) { bh[nt] = bhn[nt]; bl[nt] = bln[nt]; }
        }
    }
}

template<int NTW>
__device__ __forceinline__ void acc_zero(f32x4 (&acc)[2][NTW]) {
    #pragma unroll
    for (int a = 0; a < 2; ++a)
        #pragma unroll
        for (int b = 0; b < NTW; ++b) {
            f32x4 z = {0.f, 0.f, 0.f, 0.f};
            acc[a][b] = z;
        }
}

// bias + optional relu, split to hi/lo, store in FRAG layout for next step
template<int NTW, bool RELU>
__device__ __forceinline__ void acc_to_lds(
        f32x4 (&acc)[2][NTW], const float* __restrict__ bias,
        int w, int lane, ushort_t* Ah, ushort_t* Al) {
    int fr = lane & 15, fq = lane >> 4;
    int col0 = w * (16 * NTW);
    #pragma unroll
    for (int mt = 0; mt < 2; ++mt)
        #pragma unroll
        for (int nt = 0; nt < NTW; ++nt) {
            int col = col0 + 16 * nt + fr;         // next-step k index
            float bb = bias[col];
            int c = col >> 5, k32 = col & 31;
            int fqn = k32 >> 3, jn = k32 & 7;
            #pragma unroll
            for (int e = 0; e < 4; ++e) {
                int r = 16 * mt + fq * 4 + e;      // 0..31
                float v = acc[mt][nt][e] + bb;
                if (RELU) v = fmaxf(v, 0.0f);
                ushort_t h = f2bf(v);
                int addr = ((c * 2) + (r >> 4)) * 512 + (fqn * 16 + (r & 15)) * 8 + jn;
                Ah[addr] = h;
                Al[addr] = f2bf(v - bf2f(h));
            }
        }
}

// stage a pre-split bf16 pair band [N][256] (row-major) into FRAG LDS
__device__ __forceinline__ void stage_pair(
        const ushort_t* __restrict__ Xh_, const ushort_t* __restrict__ Xl_,
        int row0, int tid, ushort_t* Ah, ushort_t* Al) {
    #pragma unroll
    for (int i = 0; i < 2; ++i) {
        int s = i * 512 + tid;             // 1024 short8 slots
        int r = s >> 5;                    // row 0..31
        int kq = s & 31;                   // k-octet
        short8_t vh = *(const short8_t*)&Xh_[(size_t)(row0 + r) * 256 + kq * 8];
        short8_t vl = *(const short8_t*)&Xl_[(size_t)(row0 + r) * 256 + kq * 8];
        int c = kq >> 2, fq = kq & 3;
        int addr = (c * 2 + (r >> 4)) * 512 + (fq * 16 + (r & 15)) * 8;
        *(short8_t*)&Ah[addr] = vh;
        *(short8_t*)&Al[addr] = vl;
    }
}

// ---------------- fused encoder: nf -> enc1(relu) -> enc2 -> gin(relu) -> xc ----
__global__ __launch_bounds__(512) void fused_enc_kernel(
        const float* __restrict__ nf,
        const ushort_t* __restrict__ Wh, const ushort_t* __restrict__ Wl,
        const float* __restrict__ b1, const float* __restrict__ b2,
        const float* __restrict__ b3, float* __restrict__ xc) {
    __shared__ __align__(16) ushort_t Ah[8192];
    __shared__ __align__(16) ushort_t Al[8192];
    int tid = threadIdx.x;
    int lane = tid & 63;
    int w = __builtin_amdgcn_readfirstlane(tid >> 6);   // 0..7
    int row0 = blockIdx.x * 32;
    int fr = lane & 15, fq = lane >> 4;

    // stage nf band with on-the-fly hi/lo split into frag layout
    #pragma unroll
    for (int i = 0; i < 4; ++i) {
        int s = i * 512 + tid;             // 2048 float4 slots
        int r = s >> 6, k4 = s & 63;
        float4 v = *(const float4*)&nf[(size_t)(row0 + r) * 256 + k4 * 4];
        ushort_t h0 = f2bf(v.x), h1 = f2bf(v.y), h2 = f2bf(v.z), h3 = f2bf(v.w);
        int kq = k4 >> 1, half = (k4 & 1) * 4;
        int c = kq >> 2, fqs = kq & 3;
        int addr = (c * 2 + (r >> 4)) * 512 + (fqs * 16 + (r & 15)) * 8 + half;
        *(ushort4*)&Ah[addr] = make_ushort4(h0, h1, h2, h3);
        *(ushort4*)&Al[addr] =
            make_ushort4(f2bf(v.x - bf2f(h0)), f2bf(v.y - bf2f(h1)),
                         f2bf(v.z - bf2f(h2)), f2bf(v.w - bf2f(h3)));
    }
    __syncthreads();

    f32x4 acc[2][2];
    // enc1 (relu)
    acc_zero<2>(acc);
    band_step<2>(Ah, Al, Wh, Wl, w, lane, acc);
    __syncthreads();
    acc_to_lds<2, true>(acc, b1, w, lane, Ah, Al);
    __syncthreads();
    // enc2 (no relu)
    acc_zero<2>(acc);
    band_step<2>(Ah, Al, Wh + 65536, Wl + 65536, w, lane, acc);
    __syncthreads();
    acc_to_lds<2, false>(acc, b2, w, lane, Ah, Al);
    __syncthreads();
    // gin (relu) -> xc chunk-major f32
    acc_zero<2>(acc);
    band_step<2>(Ah, Al, Wh + 131072, Wl + 131072, w, lane, acc);
    int col0 = w * 32;
    #pragma unroll
    for (int mt = 0; mt < 2; ++mt)
        #pragma unroll
        for (int nt = 0; nt < 2; ++nt) {
            int gc = col0 + 16 * nt + fr;
            float bb = b3[gc];
            #pragma unroll
            for (int e = 0; e < 4; ++e) {
                int gr = row0 + 16 * mt + fq * 4 + e;
                float v = fmaxf(acc[mt][nt][e] + bb, 0.0f);
                xc[(size_t)(gc >> 5) * CHSZ + (size_t)gr * 32 + (gc & 31)] = v;
            }
        }
}

// ---------------- gl layer band GEMM: pair -> relu -> xc f32 or pair bf16 -----
template<bool CHUNKX>
__global__ __launch_bounds__(512) void gl_band_kernel(
        const ushort_t* __restrict__ Xh_, const ushort_t* __restrict__ Xl_,
        const ushort_t* __restrict__ Wh, const ushort_t* __restrict__ Wl,
        const float* __restrict__ bias, float* __restrict__ xc,
        ushort_t* __restrict__ Yh, ushort_t* __restrict__ Yl) {
    __shared__ __align__(16) ushort_t Ah[8192];
    __shared__ __align__(16) ushort_t Al[8192];
    int tid = threadIdx.x;
    int lane = tid & 63;
    int w = __builtin_amdgcn_readfirstlane(tid >> 6);
    int row0 = blockIdx.x * 32;
    int fr = lane & 15, fq = lane >> 4;
    stage_pair(Xh_, Xl_, row0, tid, Ah, Al);
    __syncthreads();
    f32x4 acc[2][2];
    acc_zero<2>(acc);
    band_step<2>(Ah, Al, Wh, Wl, w, lane, acc);
    int col0 = w * 32;
    #pragma unroll
    for (int mt = 0; mt < 2; ++mt)
        #pragma unroll
        for (int nt = 0; nt < 2; ++nt) {
            int gc = col0 + 16 * nt + fr;
            float bb = bias[gc];
            #pragma unroll
            for (int e = 0; e < 4; ++e) {
                int gr = row0 + 16 * mt + fq * 4 + e;
                float v = fmaxf(acc[mt][nt][e] + bb, 0.0f);   // gl always relu
                if (CHUNKX) {
                    xc[(size_t)(gc >> 5) * CHSZ + (size_t)gr * 32 + (gc & 31)] = v;
                } else {
                    size_t off = (size_t)gr * 256 + gc;
                    ushort_t h = f2bf(v);
                    Yh[off] = h;
                    Yl[off] = f2bf(v - bf2f(h));
                }
            }
        }
}

// ---------------- fused output: gout -> proj(relu) -> hc1(relu) -> hc2 + mean ---
// LDS arena: [0,33792) = Ah(16K)+Al(16K) during MFMA phases, then re-used as
// WL = hc_w1 staged fp32 (64 x stride-132 = 33792 B). Pf/T1 live beside it.
// hc1 col = jj*16 + cg -> WL row-addr stride 16*132 == 2112 == 4 (mod 32)x...
// cg*132 mod 32 = cg*4: 8 bank-groups x2 with 4-way broadcast = conflict-free.
__global__ __launch_bounds__(512) void fused_out_kernel(
        const ushort_t* __restrict__ Xh_, const ushort_t* __restrict__ Xl_,
        const ushort_t* __restrict__ Wh, const ushort_t* __restrict__ Wl,
        const float* __restrict__ gout_b, const float* __restrict__ proj_b,
        const float* __restrict__ hc_w1, const float* __restrict__ hc_b1,
        const float* __restrict__ hc_w2, const float* __restrict__ hc_b2,
        float* __restrict__ ne, float* __restrict__ logits, float* __restrict__ gf) {
    __shared__ __align__(16) char arena[33792 + 16896 + 8704];
    ushort_t* Ah = (ushort_t*)arena;                    // 16 KB (MFMA phases)
    ushort_t* Al = (ushort_t*)(arena + 16384);          // 16 KB (MFMA phases)
    float* WL = (float*)arena;                          // 33792 B (hc1 phase)
    float* Pf = (float*)(arena + 33792);                // 32 x 132 f32
    float* T1 = (float*)(arena + 33792 + 16896);        // 32 x 68 f32
    int tid = threadIdx.x;
    int lane = tid & 63;
    int w = __builtin_amdgcn_readfirstlane(tid >> 6);
    int row0 = blockIdx.x * 32;
    int fr = lane & 15, fq = lane >> 4;
    stage_pair(Xh_, Xl_, row0, tid, Ah, Al);
    __syncthreads();

    // gout (no relu) -> frag LDS pair
    f32x4 acc[2][2];
    acc_zero<2>(acc);
    band_step<2>(Ah, Al, Wh + 393216, Wl + 393216, w, lane, acc);
    __syncthreads();
    acc_to_lds<2, false>(acc, gout_b, w, lane, Ah, Al);
    __syncthreads();

    // proj (relu), Mcols=128: 8 waves x 16 cols
    f32x4 acc2[2][1];
    acc_zero<1>(acc2);
    band_step<1>(Ah, Al, Wh + 458752, Wl + 458752, w, lane, acc2);
    __syncthreads();   // all Ah/Al reads done -> safe to overwrite with WL

    // write proj -> ne + Pf; concurrently stage hc_w1 -> WL (disjoint regions)
    int col0 = w * 16;
    #pragma unroll
    for (int mt = 0; mt < 2; ++mt) {
        int gc = col0 + fr;
        float bb = proj_b[gc];
        #pragma unroll
        for (int e = 0; e < 4; ++e) {
            int r = 16 * mt + fq * 4 + e;
            float v = fmaxf(acc2[mt][0][e] + bb, 0.0f);
            ne[(size_t)(row0 + r) * 128 + gc] = v;
            Pf[r * 132 + gc] = v;
        }
    }
    #pragma unroll
    for (int i = 0; i < 4; ++i) {
        int j4 = i * 512 + tid;            // 2048 float4 slots (64 x 32)
        int m = j4 >> 5, k4 = j4 & 31;
        float4 v = *(const float4*)&hc_w1[(size_t)m * 128 + k4 * 4];
        *(float4*)&WL[m * 132 + k4 * 4] = v;
    }
    __syncthreads();

    // hc1 (relu): 32 rows x 64 cols; thread = (row r, cg); col = jj*16+cg
    {
        int r = tid >> 4, cg = tid & 15;
        float a4[4];
        #pragma unroll
        for (int jj = 0; jj < 4; ++jj) a4[jj] = hc_b1[jj * 16 + cg];
        for (int k4 = 0; k4 < 32; ++k4) {
            float4 x = *(const float4*)&Pf[r * 132 + k4 * 4];
            #pragma unroll
            for (int jj = 0; jj < 4; ++jj) {
                float4 wv = *(const float4*)&WL[(jj * 16 + cg) * 132 + k4 * 4];
                a4[jj] += x.x * wv.x + x.y * wv.y + x.z * wv.z + x.w * wv.w;
            }
        }
        #pragma unroll
        for (int jj = 0; jj < 4; ++jj)
            T1[r * 68 + jj * 16 + cg] = fmaxf(a4[jj], 0.0f);
    }
    __syncthreads();

    // hc2: 32x8 logits
    if (tid < 256) {
        int r = tid >> 3, m = tid & 7;
        float s = hc_b2[m];
        #pragma unroll
        for (int k4 = 0; k4 < 16; ++k4) {
            float4 x = *(const float4*)&T1[r * 68 + k4 * 4];
            float4 wv = *(const float4*)&hc_w2[(size_t)m * 64 + k4 * 4];
            s += x.x * wv.x + x.y * wv.y + x.z * wv.z + x.w * wv.w;
        }
        logits[(size_t)(row0 + r) * 8 + m] = s;
    }

    // column-mean partial of ne band
    if (tid < 128) {
        float s = 0.0f;
        #pragma unroll 4
        for (int r = 0; r < 32; ++r) s += Pf[r * 132 + tid];
        atomicAdd(&gf[tid], s * (1.0f / (float)NNODES));
    }
}

extern "C" void kernel_launch(void* const* d_in, const int* in_sizes, int n_in,
                              void* d_out, int out_size, void* d_ws, size_t ws_size,
                              hipStream_t stream) {
    const int N = NNODES;
    const float* nf     = (const float*)d_in[0];
    const int*   ei     = (const int*)d_in[1];
    const float* enc_w1 = (const float*)d_in[2];
    const float* enc_b1 = (const float*)d_in[3];
    const float* enc_w2 = (const float*)d_in[4];
    const float* enc_b2 = (const float*)d_in[5];
    const float* gin_w  = (const float*)d_in[6];
    const float* gin_b  = (const float*)d_in[7];
    const float* gl_w   = (const float*)d_in[8];
    const float* gl_b   = (const float*)d_in[9];
    const float* gout_w = (const float*)d_in[10];
    const float* gout_b = (const float*)d_in[11];
    const float* proj_w = (const float*)d_in[12];
    const float* proj_b = (const float*)d_in[13];
    const float* hc_w1  = (const float*)d_in[14];
    const float* hc_b1  = (const float*)d_in[15];
    const float* hc_w2  = (const float*)d_in[16];
    const float* hc_b2  = (const float*)d_in[17];
    const int E = in_sizes[1] >> 1;

    // workspace carve (bytes): same as rounds 8-11
    char* ws = (char*)d_ws;
    u64* M  = (u64*)ws;
    u64* MT = M + (size_t)N * WORDS;
    float*    xc  = (float*)ws;                                 // 12,591,104
    ushort_t* pAh = (ushort_t*)(ws + 12591104);                 //  6,291,456
    ushort_t* pAl = (ushort_t*)(ws + 18882560);
    ushort_t* pBh = (ushort_t*)(ws + 25174016);
    ushort_t* pBl = (ushort_t*)(ws + 31465472);                 // ends 37,756,928
    ushort_t* ell = (ushort_t*)(ws + 37756928);                 //  6,291,456
    int*      cntb = (int*)(ws + 44048384);
    float*    dinv = (float*)(ws + 44097536);
    ushort_t* Whi  = (ushort_t*)(ws + 44146688);                //    983,040
    ushort_t* Wlo  = (ushort_t*)(ws + 45129728);                //    983,040

    float* ne     = (float*)d_out;                        // [N,128]
    float* logits = ne + (size_t)N * 128;                 // [N,8]
    float* gf     = logits + (size_t)N * 8;               // [128]

    hipMemsetAsync(M, 0, 2 * (size_t)N * WORDS * sizeof(u64), stream);
    hipMemsetAsync(gf, 0, 128 * sizeof(float), stream);

    build_mask_kernel<<<(E + 255) / 256, 256, 0, stream>>>(ei, M, MT, E);
    ell_fill_kernel<<<N / 4, 256, 0, stream>>>(M, MT, ell, cntb, dinv);
    // masks dead from here; xc/pairs may clobber them
    clear_pad_kernel<<<1, 256, 0, stream>>>(xc);
    wprep_kernel<<<1920, 256, 0, stream>>>(enc_w1, enc_w2, gin_w, gl_w, gout_w, proj_w,
                                           Whi, Wlo);

    const int GB = N / 32;   // 384 band blocks (512 threads / 8 waves each)
    // encoder chain fused: nf -> xc
    fused_enc_kernel<<<GB, 512, 0, stream>>>(nf, Whi, Wlo, enc_b1, enc_b2, gin_b, xc);

    for (int i = 0; i < 3; ++i) {
        spmm_chunk_kernel<<<(N / 32) * 8, 256, 0, stream>>>(xc, ell, cntb, dinv, pAh, pAl);
        if (i < 2) {
            gl_band_kernel<true><<<GB, 512, 0, stream>>>(
                pAh, pAl, Whi + 196608 + 65536 * i, Wlo + 196608 + 65536 * i,
                gl_b + 256 * i, xc, nullptr, nullptr);
        } else {
            gl_band_kernel<false><<<GB, 512, 0, stream>>>(
                pAh, pAl, Whi + 196608 + 65536 * i, Wlo + 196608 + 65536 * i,
                gl_b + 256 * i, nullptr, pBh, pBl);
        }
    }
    // output chain fused: pB -> ne, logits, gf
    fused_out_kernel<<<GB, 512, 0, stream>>>(
        pBh, pBl, Whi, Wlo, gout_b, proj_b, hc_w1, hc_b1, hc_w2, hc_b2,
        ne, logits, gf);
}